// Round 1
// baseline (6421.288 us; speedup 1.0000x reference)
//
#include <hip/hip_runtime.h>
#include <hip/hip_bf16.h>
#include <math.h>

#define BB   16
#define CCH  64
#define NPT  32768
#define RR   32
#define R3   32768
#define GSZ  262144   // 8 channels * R3 (= 8 ch * NPT for point branch)

// ---------------- block reduction helpers (blockDim multiple of 64) -------------
__device__ __forceinline__ float blockReduceSumF(float v) {
    __shared__ float sm[16];
    #pragma unroll
    for (int o = 32; o > 0; o >>= 1) v += __shfl_down(v, o);
    __syncthreads();
    if ((threadIdx.x & 63) == 0) sm[threadIdx.x >> 6] = v;
    __syncthreads();
    float s = 0.f;
    int nw = blockDim.x >> 6;
    for (int i = 0; i < nw; ++i) s += sm[i];
    return s;
}

__device__ __forceinline__ float blockReduceMaxF(float v) {
    __shared__ float sm[16];
    #pragma unroll
    for (int o = 32; o > 0; o >>= 1) v = fmaxf(v, __shfl_down(v, o));
    __syncthreads();
    if ((threadIdx.x & 63) == 0) sm[threadIdx.x >> 6] = v;
    __syncthreads();
    float s = sm[0];
    int nw = blockDim.x >> 6;
    for (int i = 1; i < nw; ++i) s = fmaxf(s, sm[i]);
    return s;
}

__device__ __forceinline__ double blockReduceSumD(double v) {
    __shared__ double sm[16];
    #pragma unroll
    for (int o = 32; o > 0; o >>= 1) v += __shfl_down(v, o);
    __syncthreads();
    if ((threadIdx.x & 63) == 0) sm[threadIdx.x >> 6] = v;
    __syncthreads();
    double s = 0.0;
    int nw = blockDim.x >> 6;
    for (int i = 0; i < nw; ++i) s += sm[i];
    return s;
}

// ---------------- 1. per-batch coord stats: mean(3), scale ----------------------
__global__ void k_coord_stats(const float* __restrict__ coords, float* __restrict__ cstat) {
    int b = blockIdx.x;
    const float* cb = coords + (size_t)b * 3 * NPT;
    float sx = 0.f, sy = 0.f, sz = 0.f;
    for (int n = threadIdx.x; n < NPT; n += 256) {
        sx += cb[n]; sy += cb[NPT + n]; sz += cb[2 * NPT + n];
    }
    sx = blockReduceSumF(sx);
    sy = blockReduceSumF(sy);
    sz = blockReduceSumF(sz);
    float mx = sx / NPT, my = sy / NPT, mz = sz / NPT;
    float mn = 0.f;
    for (int n = threadIdx.x; n < NPT; n += 256) {
        float x = cb[n] - mx, y = cb[NPT + n] - my, z = cb[2 * NPT + n] - mz;
        mn = fmaxf(mn, sqrtf(x * x + y * y + z * z));
    }
    mn = blockReduceMaxF(mn);
    if (threadIdx.x == 0) {
        cstat[b * 4 + 0] = mx;
        cstat[b * 4 + 1] = my;
        cstat[b * 4 + 2] = mz;
        cstat[b * 4 + 3] = 2.f * mn;   // scale
    }
}

// ---------------- 2. normalized coords + voxel idx + coords passthrough ---------
__global__ void k_norm_idx(const float* __restrict__ coords, const float* __restrict__ cstat,
                           float* __restrict__ normc, int* __restrict__ vidx,
                           float* __restrict__ out2) {
    int t = blockIdx.x * 256 + threadIdx.x;   // over B*NPT (exact)
    int b = t >> 15, n = t & 32767;
    float mx = cstat[b * 4 + 0], my = cstat[b * 4 + 1], mz = cstat[b * 4 + 2];
    float scale = cstat[b * 4 + 3];
    const float* cb = coords + (size_t)b * 3 * NPT;
    float x = cb[n], y = cb[NPT + n], z = cb[2 * NPT + n];
    float nx = fminf(fmaxf(((x - mx) / scale + 0.5f) * 32.f, 0.f), 31.f);
    float ny = fminf(fmaxf(((y - my) / scale + 0.5f) * 32.f, 0.f), 31.f);
    float nz = fminf(fmaxf(((z - mz) / scale + 0.5f) * 32.f, 0.f), 31.f);
    float* nb = normc + (size_t)b * 3 * NPT;
    nb[n] = nx; nb[NPT + n] = ny; nb[2 * NPT + n] = nz;
    int vx = (int)rintf(nx), vy = (int)rintf(ny), vz = (int)rintf(nz); // half-to-even like jnp.round
    vidx[t] = (vx * 32 + vy) * 32 + vz;
    float* o2 = out2 + (size_t)b * 3 * NPT;
    o2[n] = x; o2[NPT + n] = y; o2[2 * NPT + n] = z;
}

// ---------------- 3. scatter-add features + counts ------------------------------
__global__ void k_scatter(const float* __restrict__ feat, const int* __restrict__ vidx,
                          float* __restrict__ vox, float* __restrict__ cnt) {
    int t = blockIdx.x * 256 + threadIdx.x;
    int b = t >> 15, n = t & 32767;
    int i = vidx[t];
    atomicAdd(&cnt[(b << 15) + i], 1.f);
    const float* fb = feat + (((size_t)b * CCH) << 15) + n;
    float* vb = vox + (((size_t)b * CCH) << 15) + i;
    #pragma unroll 4
    for (int c = 0; c < CCH; ++c)
        atomicAdd(&vb[((size_t)c) << 15], fb[((size_t)c) << 15]);
}

// ---------------- 4. divide by counts -------------------------------------------
__global__ void k_divide(float* __restrict__ vox, const float* __restrict__ cnt) {
    int t = blockIdx.x * 256 + threadIdx.x;  // over B*CCH*R3 (exact)
    int b = t >> 21;
    int v = t & (R3 - 1);
    vox[t] = vox[t] / fmaxf(cnt[(b << 15) + v], 1.f);
}

// ---------------- 5. direct 3x3x3 conv, fp32, LDS tiled -------------------------
#define CIC 4
#define COC 16
__global__ __launch_bounds__(256) void k_conv(const float* __restrict__ in,
                                              const float* __restrict__ w,
                                              const float* __restrict__ bias,
                                              float* __restrict__ out) {
    __shared__ float s_in[CIC][6][10][34];
    __shared__ float s_w[CIC][27][COC];
    int zy = blockIdx.x;              // 0..31
    int z0 = (zy >> 2) << 2;          // 8 z-tiles of 4
    int y0 = (zy & 3) << 3;           // 4 y-tiles of 8
    int co0 = blockIdx.y << 4;        // 4 co chunks of 16
    int b = blockIdx.z;
    int tid = threadIdx.x;
    int tx = tid & 31, ty = tid >> 5; // x 0..31, y 0..7
    float acc[4][COC];
    #pragma unroll
    for (int z = 0; z < 4; ++z)
        #pragma unroll
        for (int c = 0; c < COC; ++c) acc[z][c] = 0.f;
    const float* inb = in + (((size_t)b * CCH) << 15);

    for (int ci0 = 0; ci0 < CCH; ci0 += CIC) {
        for (int e = tid; e < CIC * 6 * 10 * 34; e += 256) {
            int xx = e % 34; int r = e / 34;
            int yy = r % 10; r /= 10;
            int zz = r % 6;  int ci = r / 6;
            int gz = z0 + zz - 1, gy = y0 + yy - 1, gx = xx - 1;
            float v = 0.f;
            if ((unsigned)gz < 32u && (unsigned)gy < 32u && (unsigned)gx < 32u)
                v = inb[(((size_t)(ci0 + ci)) << 15) + (gz << 10) + (gy << 5) + gx];
            s_in[ci][zz][yy][xx] = v;
        }
        for (int e = tid; e < COC * CIC * 27; e += 256) {
            int k = e % 27; int r = e / 27;
            int ci = r % CIC; int co = r / CIC;
            s_w[ci][k][co] = w[(size_t)(co0 + co) * (CCH * 27) + (size_t)(ci0 + ci) * 27 + k];
        }
        __syncthreads();
        #pragma unroll
        for (int ci = 0; ci < CIC; ++ci) {
            #pragma unroll
            for (int k = 0; k < 27; ++k) {
                int dz = k / 9, dy = (k % 9) / 3, dx = k % 3;
                float4 wa = *(const float4*)&s_w[ci][k][0];
                float4 wb = *(const float4*)&s_w[ci][k][4];
                float4 wc = *(const float4*)&s_w[ci][k][8];
                float4 wd = *(const float4*)&s_w[ci][k][12];
                #pragma unroll
                for (int zz = 0; zz < 4; ++zz) {
                    float iv = s_in[ci][zz + dz][ty + dy][tx + dx];
                    acc[zz][0]  += iv * wa.x; acc[zz][1]  += iv * wa.y;
                    acc[zz][2]  += iv * wa.z; acc[zz][3]  += iv * wa.w;
                    acc[zz][4]  += iv * wb.x; acc[zz][5]  += iv * wb.y;
                    acc[zz][6]  += iv * wb.z; acc[zz][7]  += iv * wb.w;
                    acc[zz][8]  += iv * wc.x; acc[zz][9]  += iv * wc.y;
                    acc[zz][10] += iv * wc.z; acc[zz][11] += iv * wc.w;
                    acc[zz][12] += iv * wd.x; acc[zz][13] += iv * wd.y;
                    acc[zz][14] += iv * wd.z; acc[zz][15] += iv * wd.w;
                }
            }
        }
        __syncthreads();
    }
    #pragma unroll
    for (int co = 0; co < COC; ++co) {
        float bi = bias[co0 + co];
        #pragma unroll
        for (int zz = 0; zz < 4; ++zz)
            out[(((size_t)(b * CCH + co0 + co)) << 15) + ((z0 + zz) << 10) + ((y0 + ty) << 5) + tx]
                = acc[zz][co] + bi;
    }
}

// ---------------- 6. group-norm stats (per b,g over contiguous 262144) ----------
__global__ void k_gn_stats(const float* __restrict__ x, float* __restrict__ st) {
    int bg = blockIdx.x;   // 0..127
    const float* p = x + (size_t)bg * GSZ;
    double s = 0.0, s2 = 0.0;
    for (int i = threadIdx.x; i < GSZ; i += blockDim.x) {
        float v = p[i];
        s += v; s2 += (double)v * (double)v;
    }
    s  = blockReduceSumD(s);
    s2 = blockReduceSumD(s2);
    if (threadIdx.x == 0) {
        double mean = s / GSZ;
        double var = s2 / GSZ - mean * mean;
        st[bg * 2 + 0] = (float)mean;
        st[bg * 2 + 1] = (float)(1.0 / sqrt(var + 1e-5));
    }
}

// ---------------- 7. group-norm apply + swish, in place -------------------------
__global__ void k_gn_apply(float* __restrict__ x, const float* __restrict__ st,
                           const float* __restrict__ gamma, const float* __restrict__ beta) {
    int t = blockIdx.x * 256 + threadIdx.x;   // over B*CCH*R3 (exact)
    int bg = t >> 18;
    int c = (t >> 15) & 63;
    float mean = st[bg * 2 + 0], rstd = st[bg * 2 + 1];
    float v = (x[t] - mean) * rstd * gamma[c] + beta[c];
    x[t] = v / (1.f + expf(-v));
}

// ---------------- 8. point branch GEMM: out1 = wp @ feat + bp -------------------
__global__ __launch_bounds__(256) void k_point(const float* __restrict__ feat,
                                               const float* __restrict__ wp,
                                               const float* __restrict__ bp,
                                               float* __restrict__ out1) {
    __shared__ float s_f[64][64];
    __shared__ float s_w[64][68];
    int nblk = blockIdx.x * 64;
    int b = blockIdx.y;
    int tid = threadIdx.x;
    const float* fb = feat + (((size_t)b * CCH) << 15);
    for (int e = tid; e < 64 * 64; e += 256) {
        int c = e >> 6, nn = e & 63;
        s_f[c][nn] = fb[(((size_t)c) << 15) + nblk + nn];
        s_w[nn][c] = wp[e];   // wp[o=c][c=nn] -> s_w[cin][o]
    }
    __syncthreads();
    int o0 = (tid >> 4) << 2;
    int n0 = (tid & 15) << 2;
    float acc[4][4] = {{0.f}};
    for (int c = 0; c < 64; ++c) {
        float4 fv = *(const float4*)&s_f[c][n0];
        float4 wv = *(const float4*)&s_w[c][o0];
        float fvv[4] = {fv.x, fv.y, fv.z, fv.w};
        float wvv[4] = {wv.x, wv.y, wv.z, wv.w};
        #pragma unroll
        for (int j = 0; j < 4; ++j)
            #pragma unroll
            for (int i = 0; i < 4; ++i) acc[j][i] += wvv[j] * fvv[i];
    }
    #pragma unroll
    for (int j = 0; j < 4; ++j) {
        float bb = bp[o0 + j];
        float* op = out1 + (((size_t)(b * CCH + o0 + j)) << 15) + nblk + n0;
        float4 r = make_float4(acc[j][0] + bb, acc[j][1] + bb, acc[j][2] + bb, acc[j][3] + bb);
        *(float4*)op = r;
    }
}

// ---------------- 9. final: trilinear devox + point GN/swish + add --------------
__global__ void k_final(const float* __restrict__ h2, const float* __restrict__ normc,
                        const float* __restrict__ gnp, const float* __restrict__ gp,
                        const float* __restrict__ bep, float* __restrict__ out1) {
    int t = blockIdx.x * 256 + threadIdx.x;   // over B*NPT (exact)
    int b = t >> 15, n = t & 32767;
    const float* nb = normc + (size_t)b * 3 * NPT;
    float nx = nb[n], ny = nb[NPT + n], nz = nb[2 * NPT + n];
    float fxf = floorf(nx), fyf = floorf(ny), fzf = floorf(nz);
    float fx = nx - fxf, fy = ny - fyf, fz = nz - fzf;
    int x0 = (int)fxf; x0 = x0 < 31 ? x0 : 31;
    int y0 = (int)fyf; y0 = y0 < 31 ? y0 : 31;
    int z0 = (int)fzf; z0 = z0 < 31 ? z0 : 31;
    int x1 = x0 + 1 < 31 ? x0 + 1 : 31;
    int y1 = y0 + 1 < 31 ? y0 + 1 : 31;
    int z1 = z0 + 1 < 31 ? z0 + 1 : 31;
    float wx0 = 1.f - fx, wx1 = fx, wy0 = 1.f - fy, wy1 = fy, wz0 = 1.f - fz, wz1 = fz;
    int i000 = (x0 * 32 + y0) * 32 + z0;
    int i001 = (x0 * 32 + y0) * 32 + z1;
    int i010 = (x0 * 32 + y1) * 32 + z0;
    int i011 = (x0 * 32 + y1) * 32 + z1;
    int i100 = (x1 * 32 + y0) * 32 + z0;
    int i101 = (x1 * 32 + y0) * 32 + z1;
    int i110 = (x1 * 32 + y1) * 32 + z0;
    int i111 = (x1 * 32 + y1) * 32 + z1;
    float w000 = wx0 * wy0 * wz0, w001 = wx0 * wy0 * wz1;
    float w010 = wx0 * wy1 * wz0, w011 = wx0 * wy1 * wz1;
    float w100 = wx1 * wy0 * wz0, w101 = wx1 * wy0 * wz1;
    float w110 = wx1 * wy1 * wz0, w111 = wx1 * wy1 * wz1;
    const float* hb = h2 + (((size_t)b * CCH) << 15);
    float* ob = out1 + (((size_t)b * CCH) << 15) + n;
    for (int c = 0; c < CCH; ++c) {
        const float* hc = hb + (((size_t)c) << 15);
        float acc = w000 * hc[i000] + w001 * hc[i001] + w010 * hc[i010] + w011 * hc[i011]
                  + w100 * hc[i100] + w101 * hc[i101] + w110 * hc[i110] + w111 * hc[i111];
        float pv = ob[((size_t)c) << 15];
        int bg = (b << 3) + (c >> 3);
        float mean = gnp[bg * 2 + 0], rstd = gnp[bg * 2 + 1];
        float g = (pv - mean) * rstd * gp[c] + bep[c];
        float sw = g / (1.f + expf(-g));
        ob[((size_t)c) << 15] = acc + sw;
    }
}

// --------------------------------- launcher -------------------------------------
extern "C" void kernel_launch(void* const* d_in, const int* in_sizes, int n_in,
                              void* d_out, int out_size, void* d_ws, size_t ws_size,
                              hipStream_t stream) {
    const float* feat   = (const float*)d_in[0];
    const float* coords = (const float*)d_in[1];
    const float* w1  = (const float*)d_in[2];
    const float* b1  = (const float*)d_in[3];
    const float* g1  = (const float*)d_in[4];
    const float* be1 = (const float*)d_in[5];
    const float* w2  = (const float*)d_in[6];
    const float* b2  = (const float*)d_in[7];
    const float* g2  = (const float*)d_in[8];
    const float* be2 = (const float*)d_in[9];
    const float* wp  = (const float*)d_in[10];
    const float* bp  = (const float*)d_in[11];
    const float* gp  = (const float*)d_in[12];
    const float* bep = (const float*)d_in[13];

    float* out1 = (float*)d_out;
    float* out2 = out1 + (size_t)BB * CCH * NPT;

    float* voxA  = (float*)d_ws;
    float* voxB  = voxA + (size_t)BB * CCH * R3;
    float* cnt   = voxB + (size_t)BB * CCH * R3;
    float* normc = cnt + (size_t)BB * R3;
    int*   vidx  = (int*)(normc + (size_t)BB * 3 * NPT);
    float* cstat = (float*)(vidx + (size_t)BB * NPT);
    float* gn1 = cstat + 64;
    float* gn2 = gn1 + 256;
    float* gnp = gn2 + 256;

    hipMemsetAsync(voxA, 0, (size_t)BB * CCH * R3 * sizeof(float), stream);
    hipMemsetAsync(cnt, 0, (size_t)BB * R3 * sizeof(float), stream);

    k_coord_stats<<<BB, 256, 0, stream>>>(coords, cstat);
    k_norm_idx<<<(BB * NPT) / 256, 256, 0, stream>>>(coords, cstat, normc, vidx, out2);
    k_scatter<<<(BB * NPT) / 256, 256, 0, stream>>>(feat, vidx, voxA, cnt);
    k_divide<<<(BB * CCH * R3) / 256, 256, 0, stream>>>(voxA, cnt);

    k_conv<<<dim3(32, 4, BB), 256, 0, stream>>>(voxA, w1, b1, voxB);
    k_gn_stats<<<128, 1024, 0, stream>>>(voxB, gn1);
    k_gn_apply<<<(BB * CCH * R3) / 256, 256, 0, stream>>>(voxB, gn1, g1, be1);

    k_conv<<<dim3(32, 4, BB), 256, 0, stream>>>(voxB, w2, b2, voxA);
    k_gn_stats<<<128, 1024, 0, stream>>>(voxA, gn2);
    k_gn_apply<<<(BB * CCH * R3) / 256, 256, 0, stream>>>(voxA, gn2, g2, be2);

    k_point<<<dim3(NPT / 64, BB), 256, 0, stream>>>(feat, wp, bp, out1);
    k_gn_stats<<<128, 1024, 0, stream>>>(out1, gnp);

    k_final<<<(BB * NPT) / 256, 256, 0, stream>>>(voxA, normc, gnp, gp, bep, out1);
}

// Round 3
// 2997.498 us; speedup vs baseline: 2.1422x; 2.1422x over previous
//
#include <hip/hip_runtime.h>
#include <hip/hip_bf16.h>
#include <math.h>

#define BB   16
#define CCH  64
#define NPT  32768
#define RR   32
#define R3   32768
#define GSZ  262144
#define VOXB 2228224   // 32*32*34*64 bf16 elements per batch (z padded to 34)

typedef __attribute__((ext_vector_type(8))) short bfx8;
typedef __attribute__((ext_vector_type(8))) unsigned short usx8;
typedef __attribute__((ext_vector_type(16))) float f32x16;

__device__ __forceinline__ short f2bf(float f) {
    unsigned u = __builtin_bit_cast(unsigned, f);
    u += 0x7fff + ((u >> 16) & 1);
    return (short)(u >> 16);
}
__device__ __forceinline__ float bf2f(unsigned short s) {
    unsigned u = ((unsigned)s) << 16;
    return __builtin_bit_cast(float, u);
}

// ---------------- block reduction helpers -------------------------------------
__device__ __forceinline__ float blockReduceSumF(float v) {
    __shared__ float sm[16];
    #pragma unroll
    for (int o = 32; o > 0; o >>= 1) v += __shfl_down(v, o);
    __syncthreads();
    if ((threadIdx.x & 63) == 0) sm[threadIdx.x >> 6] = v;
    __syncthreads();
    float s = 0.f;
    int nw = blockDim.x >> 6;
    for (int i = 0; i < nw; ++i) s += sm[i];
    return s;
}

__device__ __forceinline__ float blockReduceMaxF(float v) {
    __shared__ float sm[16];
    #pragma unroll
    for (int o = 32; o > 0; o >>= 1) v = fmaxf(v, __shfl_down(v, o));
    __syncthreads();
    if ((threadIdx.x & 63) == 0) sm[threadIdx.x >> 6] = v;
    __syncthreads();
    float s = sm[0];
    int nw = blockDim.x >> 6;
    for (int i = 1; i < nw; ++i) s = fmaxf(s, sm[i]);
    return s;
}

// ---------------- 1. per-batch coord stats ------------------------------------
__global__ void k_coord_stats(const float* __restrict__ coords, float* __restrict__ cstat) {
    int b = blockIdx.x;
    const float* cb = coords + (size_t)b * 3 * NPT;
    float sx = 0.f, sy = 0.f, sz = 0.f;
    for (int n = threadIdx.x; n < NPT; n += 256) {
        sx += cb[n]; sy += cb[NPT + n]; sz += cb[2 * NPT + n];
    }
    sx = blockReduceSumF(sx);
    sy = blockReduceSumF(sy);
    sz = blockReduceSumF(sz);
    float mx = sx / NPT, my = sy / NPT, mz = sz / NPT;
    float mn = 0.f;
    for (int n = threadIdx.x; n < NPT; n += 256) {
        float x = cb[n] - mx, y = cb[NPT + n] - my, z = cb[2 * NPT + n] - mz;
        mn = fmaxf(mn, sqrtf(x * x + y * y + z * z));
    }
    mn = blockReduceMaxF(mn);
    if (threadIdx.x == 0) {
        cstat[b * 4 + 0] = mx;
        cstat[b * 4 + 1] = my;
        cstat[b * 4 + 2] = mz;
        cstat[b * 4 + 3] = 2.f * mn;
    }
}

// ---------------- 2. normalized coords + voxel idx + coords passthrough --------
__global__ void k_norm_idx(const float* __restrict__ coords, const float* __restrict__ cstat,
                           float* __restrict__ normc, int* __restrict__ vidx,
                           float* __restrict__ out2) {
    int t = blockIdx.x * 256 + threadIdx.x;
    int b = t >> 15, n = t & 32767;
    float mx = cstat[b * 4 + 0], my = cstat[b * 4 + 1], mz = cstat[b * 4 + 2];
    float scale = cstat[b * 4 + 3];
    const float* cb = coords + (size_t)b * 3 * NPT;
    float x = cb[n], y = cb[NPT + n], z = cb[2 * NPT + n];
    float nx = fminf(fmaxf(((x - mx) / scale + 0.5f) * 32.f, 0.f), 31.f);
    float ny = fminf(fmaxf(((y - my) / scale + 0.5f) * 32.f, 0.f), 31.f);
    float nz = fminf(fmaxf(((z - mz) / scale + 0.5f) * 32.f, 0.f), 31.f);
    float* nb = normc + (size_t)b * 3 * NPT;
    nb[n] = nx; nb[NPT + n] = ny; nb[2 * NPT + n] = nz;
    int vx = (int)rintf(nx), vy = (int)rintf(ny), vz = (int)rintf(nz);
    vidx[t] = (vx * 32 + vy) * 32 + vz;
    float* o2 = out2 + (size_t)b * 3 * NPT;
    o2[n] = x; o2[NPT + n] = y; o2[2 * NPT + n] = z;
}

// ---------------- 3. scatter-add features [b][vox][c] + counts -----------------
__global__ void k_scatter(const float* __restrict__ feat, const int* __restrict__ vidx,
                          float* __restrict__ scat, float* __restrict__ cnt) {
    int t = blockIdx.x * 256 + threadIdx.x;
    int b = t >> 15, n = t & 32767;
    int i = vidx[t];
    atomicAdd(&cnt[(b << 15) + i], 1.f);
    const float* fb = feat + (((size_t)b * CCH) << 15) + n;
    float* vb = scat + ((((size_t)b << 15) + i) << 6);
    #pragma unroll 4
    for (int c = 0; c < CCH; ++c)
        atomicAdd(&vb[c], fb[((size_t)c) << 15]);
}

// ---------------- 4. divide + relayout to padded bf16 [x][y][z34][ci] ----------
__global__ void k_div_relayout(const float* __restrict__ scat, const float* __restrict__ cnt,
                               short* __restrict__ vout) {
    int e4 = blockIdx.x * 256 + threadIdx.x;   // over 16*32768*16
    int c4 = e4 & 15, vx = (e4 >> 4) & 32767, b = e4 >> 19;
    float rc = 1.f / fmaxf(cnt[(b << 15) + vx], 1.f);
    const float4 f = *(const float4*)(scat + ((((size_t)b << 15) + vx) << 6) + c4 * 4);
    short4 pk;
    pk.x = f2bf(f.x * rc); pk.y = f2bf(f.y * rc);
    pk.z = f2bf(f.z * rc); pk.w = f2bf(f.w * rc);
    *(short4*)(vout + (size_t)b * VOXB + ((size_t)(vx >> 5) * 34 + (vx & 31) + 1) * 64 + c4 * 4) = pk;
}

// ---------------- 5. weight transpose: [co][ci][27] f32 -> [k][co][ci] bf16 ----
__global__ void k_wprep(const float* __restrict__ w, short* __restrict__ wT) {
    int e = blockIdx.x * 256 + threadIdx.x;   // 27*64*64 = 110592
    int ci = e & 63, co = (e >> 6) & 63, k = e >> 12;
    wT[e] = f2bf(w[(size_t)(co * 64 + ci) * 27 + k]);
}

// ---------------- 6. MFMA implicit-GEMM 3x3x3 conv -----------------------------
__global__ __launch_bounds__(256, 2) void k_conv_mfma(
    const short* __restrict__ vin, const short* __restrict__ wT,
    const float* __restrict__ bias, short* __restrict__ vout)
{
    int bid = blockIdx.x;                 // 1024 = 8 xcd * 2 b * 64 tiles
    int xcd = bid & 7, sub = bid >> 3;
    int b = (xcd << 1) | (sub >> 6);
    int tile = sub & 63;
    int x0 = (tile >> 3) << 2, y0 = (tile & 7) << 2;
    int tid = threadIdx.x;
    int wv = tid >> 6, l = tid & 63;
    int lo = l & 31, hi = l >> 5;
    int laneoff = lo * 64 + hi * 8;
    const short* vb = vin + (size_t)b * VOXB;

    f32x16 acc[2][4];
    #pragma unroll
    for (int cb = 0; cb < 2; ++cb)
        #pragma unroll
        for (int j = 0; j < 4; ++j)
            #pragma unroll
            for (int i = 0; i < 16; ++i) acc[cb][j][i] = 0.f;

    int xo = x0 + wv;   // this wave's output x line

    for (int tap = 0; tap < 27; ++tap) {
        int dx = tap / 9, dy = (tap / 3) % 3, dz = tap % 3;
        int xi = xo + dx - 1;
        if ((unsigned)xi >= 32u) continue;
        const short* wt = wT + tap * 4096 + laneoff;
        const short* lb[4];
        bool val[4];
        #pragma unroll
        for (int j = 0; j < 4; ++j) {
            int yi = y0 + j + dy - 1;
            val[j] = (unsigned)yi < 32u;
            lb[j] = vb + ((size_t)(xi * 32 + (yi & 31)) * 34 + dz) * 64 + laneoff;
        }
        #pragma unroll 2
        for (int cs = 0; cs < 4; ++cs) {
            bfx8 a0 = *(const bfx8*)(wt + cs * 16);
            bfx8 a1 = *(const bfx8*)(wt + 2048 + cs * 16);
            #pragma unroll
            for (int j = 0; j < 4; ++j) {
                if (!val[j]) continue;
                bfx8 bv = *(const bfx8*)(lb[j] + cs * 16);
                acc[0][j] = __builtin_amdgcn_mfma_f32_32x32x16_bf16(a0, bv, acc[0][j], 0, 0, 0);
                acc[1][j] = __builtin_amdgcn_mfma_f32_32x32x16_bf16(a1, bv, acc[1][j], 0, 0, 0);
            }
        }
    }

    short* ob = vout + (size_t)b * VOXB;
    #pragma unroll
    for (int cb = 0; cb < 2; ++cb) {
        #pragma unroll
        for (int j = 0; j < 4; ++j) {
            size_t rb = ((size_t)(xo * 32 + y0 + j) * 34 + 1 + lo) * 64;
            #pragma unroll
            for (int q = 0; q < 4; ++q) {
                int co0 = cb * 32 + hi * 4 + q * 8;
                short4 pk;
                pk.x = f2bf(acc[cb][j][q * 4 + 0] + bias[co0 + 0]);
                pk.y = f2bf(acc[cb][j][q * 4 + 1] + bias[co0 + 1]);
                pk.z = f2bf(acc[cb][j][q * 4 + 2] + bias[co0 + 2]);
                pk.w = f2bf(acc[cb][j][q * 4 + 3] + bias[co0 + 3]);
                *(short4*)(ob + rb + co0) = pk;
            }
        }
    }
}

// ---------------- 7. GN stats on padded bf16 volume (atomic partial sums) ------
__global__ void k_gn_stats_b(const short* __restrict__ v, float* __restrict__ st) {
    int b = blockIdx.x >> 3, p = blockIdx.x & 7;
    int tid = threadIdx.x;
    int cg = tid & 7, lv = tid >> 3;   // cg = channel group (=GN group), lv = 0..31
    const short* vb = v + (size_t)b * VOXB + cg * 8;
    float s = 0.f, s2 = 0.f;
    for (int i = 0; i < 128; ++i) {
        int vx = p * 4096 + i * 32 + lv;
        usx8 hv = *(const usx8*)(vb + ((size_t)(vx >> 5) * 34 + (vx & 31) + 1) * 64);
        #pragma unroll
        for (int k = 0; k < 8; ++k) {
            float f = bf2f(hv[k]);
            s += f; s2 = fmaf(f, f, s2);
        }
    }
    #pragma unroll
    for (int o = 8; o < 64; o <<= 1) { s += __shfl_xor(s, o); s2 += __shfl_xor(s2, o); }
    __shared__ float sm[4][8][2];
    if ((tid & 63) < 8) { sm[tid >> 6][cg][0] = s; sm[tid >> 6][cg][1] = s2; }
    __syncthreads();
    if (tid < 8) {
        float a = 0.f, a2 = 0.f;
        #pragma unroll
        for (int w = 0; w < 4; ++w) { a += sm[w][tid][0]; a2 += sm[w][tid][1]; }
        atomicAdd(&st[(b * 8 + tid) * 2 + 0], a);
        atomicAdd(&st[(b * 8 + tid) * 2 + 1], a2);
    }
}

// ---------------- 8. GN apply + swish, in place on padded bf16 volume ----------
__global__ void k_gn_apply_b(short* __restrict__ v, const float* __restrict__ st,
                             const float* __restrict__ gamma, const float* __restrict__ beta) {
    int e = blockIdx.x * 256 + threadIdx.x;   // over 16*32768*8
    int cg = e & 7, vx = (e >> 3) & 32767, b = e >> 18;
    float s = st[(b * 8 + cg) * 2 + 0], s2 = st[(b * 8 + cg) * 2 + 1];
    float mean = s * (1.f / 262144.f);
    float var = s2 * (1.f / 262144.f) - mean * mean;
    float rstd = rsqrtf(var + 1e-5f);
    short* p = v + (size_t)b * VOXB + ((size_t)(vx >> 5) * 34 + (vx & 31) + 1) * 64 + cg * 8;
    usx8 hv = *(const usx8*)p;
    usx8 ov;
    #pragma unroll
    for (int i = 0; i < 8; ++i) {
        int co = cg * 8 + i;
        float f = bf2f(hv[i]);
        float g = (f - mean) * rstd * gamma[co] + beta[co];
        float sw = g / (1.f + __expf(-g));
        ov[i] = (unsigned short)f2bf(sw);
    }
    *(usx8*)p = ov;
}

// ---------------- 9. point branch GEMM: out1 = wp @ feat + bp ------------------
__global__ __launch_bounds__(256) void k_point(const float* __restrict__ feat,
                                               const float* __restrict__ wp,
                                               const float* __restrict__ bp,
                                               float* __restrict__ out1) {
    __shared__ float s_f[64][64];
    __shared__ float s_w[64][68];
    int nblk = blockIdx.x * 64;
    int b = blockIdx.y;
    int tid = threadIdx.x;
    const float* fb = feat + (((size_t)b * CCH) << 15);
    for (int e = tid; e < 64 * 64; e += 256) {
        int c = e >> 6, nn = e & 63;
        s_f[c][nn] = fb[(((size_t)c) << 15) + nblk + nn];
        s_w[nn][c] = wp[e];
    }
    __syncthreads();
    int o0 = (tid >> 4) << 2;
    int n0 = (tid & 15) << 2;
    float acc[4][4] = {{0.f}};
    for (int c = 0; c < 64; ++c) {
        float4 fv = *(const float4*)&s_f[c][n0];
        float4 wv = *(const float4*)&s_w[c][o0];
        float fvv[4] = {fv.x, fv.y, fv.z, fv.w};
        float wvv[4] = {wv.x, wv.y, wv.z, wv.w};
        #pragma unroll
        for (int j = 0; j < 4; ++j)
            #pragma unroll
            for (int i = 0; i < 4; ++i) acc[j][i] += wvv[j] * fvv[i];
    }
    #pragma unroll
    for (int j = 0; j < 4; ++j) {
        float bb = bp[o0 + j];
        float* op = out1 + (((size_t)(b * CCH + o0 + j)) << 15) + nblk + n0;
        float4 r = make_float4(acc[j][0] + bb, acc[j][1] + bb, acc[j][2] + bb, acc[j][3] + bb);
        *(float4*)op = r;
    }
}

// ---------------- 10. point-branch GN stats (f32, contiguous groups) -----------
__global__ void k_gn_stats_pt(const float* __restrict__ x, float* __restrict__ st) {
    int bg = blockIdx.x;
    const float* p = x + (size_t)bg * GSZ;
    float s = 0.f, s2 = 0.f;
    for (int i = threadIdx.x; i < GSZ; i += blockDim.x) {
        float v = p[i];
        s += v; s2 = fmaf(v, v, s2);
    }
    s  = blockReduceSumF(s);
    s2 = blockReduceSumF(s2);
    if (threadIdx.x == 0) {
        float mean = s / GSZ;
        float var = s2 / GSZ - mean * mean;
        st[bg * 2 + 0] = mean;
        st[bg * 2 + 1] = rsqrtf(var + 1e-5f);
    }
}

// ---------------- 11. final: devox gather + point GN/swish + add ---------------
__global__ void k_final(const short* __restrict__ h, const float* __restrict__ normc,
                        const float* __restrict__ stp, const float* __restrict__ gp,
                        const float* __restrict__ bep, float* __restrict__ out1) {
    int tid = threadIdx.x;
    int s = tid & 7, pp = tid >> 3;
    int pt = blockIdx.x * 32 + pp;
    int b = pt >> 15, n = pt & 32767;
    const float* nb = normc + (size_t)b * 3 * NPT;
    float nx = nb[n], ny = nb[NPT + n], nz = nb[2 * NPT + n];
    float fxf = floorf(nx), fyf = floorf(ny), fzf = floorf(nz);
    float fx = nx - fxf, fy = ny - fyf, fz = nz - fzf;
    int x0 = (int)fxf; x0 = x0 < 31 ? x0 : 31;
    int y0 = (int)fyf; y0 = y0 < 31 ? y0 : 31;
    int z0 = (int)fzf; z0 = z0 < 31 ? z0 : 31;
    int x1 = x0 + 1 < 31 ? x0 + 1 : 31;
    int y1 = y0 + 1 < 31 ? y0 + 1 : 31;
    int z1 = z0 + 1 < 31 ? z0 + 1 : 31;
    float wx0 = 1.f - fx, wx1 = fx, wy0 = 1.f - fy, wy1 = fy, wz0 = 1.f - fz, wz1 = fz;
    const short* hb = h + (size_t)b * VOXB + s * 8;
    float acc[8];
    #pragma unroll
    for (int i = 0; i < 8; ++i) acc[i] = 0.f;
    #pragma unroll
    for (int cx = 0; cx < 2; ++cx) {
        int xi = cx ? x1 : x0; float wxx = cx ? wx1 : wx0;
        #pragma unroll
        for (int cy = 0; cy < 2; ++cy) {
            int yi = cy ? y1 : y0; float wyy = cy ? wy1 : wy0;
            #pragma unroll
            for (int cz = 0; cz < 2; ++cz) {
                int zi = cz ? z1 : z0; float wzz = cz ? wz1 : wz0;
                float w = wxx * wyy * wzz;
                usx8 hv = *(const usx8*)(hb + ((size_t)(xi * 32 + yi) * 34 + zi + 1) * 64);
                #pragma unroll
                for (int i = 0; i < 8; ++i) acc[i] = fmaf(w, bf2f(hv[i]), acc[i]);
            }
        }
    }
    float mean = stp[(b * 8 + s) * 2 + 0], rstd = stp[(b * 8 + s) * 2 + 1];
    #pragma unroll
    for (int i = 0; i < 8; ++i) {
        int co = s * 8 + i;
        float* op = out1 + (((size_t)(b * CCH + co)) << 15) + n;
        float pv = *op;
        float g = (pv - mean) * rstd * gp[co] + bep[co];
        float sw = g / (1.f + __expf(-g));
        *op = acc[i] + sw;
    }
}

// --------------------------------- launcher ------------------------------------
extern "C" void kernel_launch(void* const* d_in, const int* in_sizes, int n_in,
                              void* d_out, int out_size, void* d_ws, size_t ws_size,
                              hipStream_t stream) {
    const float* feat   = (const float*)d_in[0];
    const float* coords = (const float*)d_in[1];
    const float* w1  = (const float*)d_in[2];
    const float* b1  = (const float*)d_in[3];
    const float* g1  = (const float*)d_in[4];
    const float* be1 = (const float*)d_in[5];
    const float* w2  = (const float*)d_in[6];
    const float* b2  = (const float*)d_in[7];
    const float* g2  = (const float*)d_in[8];
    const float* be2 = (const float*)d_in[9];
    const float* wp  = (const float*)d_in[10];
    const float* bp  = (const float*)d_in[11];
    const float* gp  = (const float*)d_in[12];
    const float* bep = (const float*)d_in[13];

    float* out1 = (float*)d_out;
    float* out2 = out1 + (size_t)BB * CCH * NPT;

    // workspace layout (~216 MB)
    const size_t scatBytes = (size_t)BB * R3 * CCH * 4;       // 134 MB, later reused as voxT_mid
    float* scat     = (float*)d_ws;
    short* voxT_mid = (short*)d_ws;                            // alias (71 MB <= 134 MB)
    short* voxT_in  = (short*)((char*)d_ws + scatBytes);
    char* p = (char*)voxT_in + (size_t)BB * VOXB * 2;
    float* cnt   = (float*)p; p += (size_t)BB * R3 * 4;
    float* normc = (float*)p; p += (size_t)BB * 3 * NPT * 4;
    int*   vidx  = (int*)p;   p += (size_t)BB * NPT * 4;
    float* cstat = (float*)p; p += 64 * 4;
    short* wT1   = (short*)p; p += 110592 * 2;
    short* wT2   = (short*)p; p += 110592 * 2;
    float* st1   = (float*)p; p += 256 * 4;
    float* st2   = (float*)p; p += 256 * 4;
    float* stp   = (float*)p; p += 256 * 4;

    hipMemsetAsync(scat, 0, scatBytes, stream);
    hipMemsetAsync(voxT_in, 0, (size_t)BB * VOXB * 2, stream);
    hipMemsetAsync(cnt, 0, (size_t)BB * R3 * 4, stream);
    hipMemsetAsync(st1, 0, 512 * 4, stream);   // st1 + st2 contiguous

    k_coord_stats<<<BB, 256, 0, stream>>>(coords, cstat);
    k_norm_idx<<<(BB * NPT) / 256, 256, 0, stream>>>(coords, cstat, normc, vidx, out2);
    k_scatter<<<(BB * NPT) / 256, 256, 0, stream>>>(feat, vidx, scat, cnt);
    k_div_relayout<<<(BB * R3 * 16) / 256, 256, 0, stream>>>(scat, cnt, voxT_in);
    k_wprep<<<432, 256, 0, stream>>>(w1, wT1);
    k_wprep<<<432, 256, 0, stream>>>(w2, wT2);

    // scat no longer needed -> becomes voxT_mid (pads must be zero)
    hipMemsetAsync(voxT_mid, 0, (size_t)BB * VOXB * 2, stream);

    k_conv_mfma<<<1024, 256, 0, stream>>>(voxT_in, wT1, b1, voxT_mid);
    k_gn_stats_b<<<128, 256, 0, stream>>>(voxT_mid, st1);
    k_gn_apply_b<<<(BB * R3 * 8) / 256, 256, 0, stream>>>(voxT_mid, st1, g1, be1);

    k_conv_mfma<<<1024, 256, 0, stream>>>(voxT_mid, wT2, b2, voxT_in);  // voxT_in pads still zero
    k_gn_stats_b<<<128, 256, 0, stream>>>(voxT_in, st2);
    k_gn_apply_b<<<(BB * R3 * 8) / 256, 256, 0, stream>>>(voxT_in, st2, g2, be2);

    k_point<<<dim3(NPT / 64, BB), 256, 0, stream>>>(feat, wp, bp, out1);
    k_gn_stats_pt<<<128, 1024, 0, stream>>>(out1, stp);

    k_final<<<(BB * NPT) / 32, 256, 0, stream>>>(voxT_in, normc, stp, gp, bep, out1);
}

// Round 4
// 1350.968 us; speedup vs baseline: 4.7531x; 2.2188x over previous
//
#include <hip/hip_runtime.h>
#include <hip/hip_bf16.h>
#include <math.h>

#define BB   16
#define CCH  64
#define NPT  32768
#define RR   32
#define R3   32768
#define GSZ  262144
#define VOXB 2228224   // 32*32*34*64 bf16 elements per batch (z padded to 34)

typedef __attribute__((ext_vector_type(8))) short bfx8;
typedef __attribute__((ext_vector_type(8))) unsigned short usx8;
typedef __attribute__((ext_vector_type(16))) float f32x16;

__device__ __forceinline__ short f2bf(float f) {
    unsigned u = __builtin_bit_cast(unsigned, f);
    u += 0x7fff + ((u >> 16) & 1);
    return (short)(u >> 16);
}
__device__ __forceinline__ float bf2f(unsigned short s) {
    unsigned u = ((unsigned)s) << 16;
    return __builtin_bit_cast(float, u);
}

// ---------------- block reduction helpers -------------------------------------
__device__ __forceinline__ float blockReduceSumF(float v) {
    __shared__ float sm[16];
    #pragma unroll
    for (int o = 32; o > 0; o >>= 1) v += __shfl_down(v, o);
    __syncthreads();
    if ((threadIdx.x & 63) == 0) sm[threadIdx.x >> 6] = v;
    __syncthreads();
    float s = 0.f;
    int nw = blockDim.x >> 6;
    for (int i = 0; i < nw; ++i) s += sm[i];
    return s;
}

__device__ __forceinline__ float blockReduceMaxF(float v) {
    __shared__ float sm[16];
    #pragma unroll
    for (int o = 32; o > 0; o >>= 1) v = fmaxf(v, __shfl_down(v, o));
    __syncthreads();
    if ((threadIdx.x & 63) == 0) sm[threadIdx.x >> 6] = v;
    __syncthreads();
    float s = sm[0];
    int nw = blockDim.x >> 6;
    for (int i = 1; i < nw; ++i) s = fmaxf(s, sm[i]);
    return s;
}

// ---------------- 1. per-batch coord stats ------------------------------------
__global__ __launch_bounds__(1024) void k_coord_stats(const float* __restrict__ coords,
                                                      float* __restrict__ cstat) {
    int b = blockIdx.x;
    const float* cb = coords + (size_t)b * 3 * NPT;
    float sx = 0.f, sy = 0.f, sz = 0.f;
    for (int n = threadIdx.x; n < NPT; n += 1024) {
        sx += cb[n]; sy += cb[NPT + n]; sz += cb[2 * NPT + n];
    }
    sx = blockReduceSumF(sx);
    sy = blockReduceSumF(sy);
    sz = blockReduceSumF(sz);
    float mx = sx / NPT, my = sy / NPT, mz = sz / NPT;
    float mn = 0.f;
    for (int n = threadIdx.x; n < NPT; n += 1024) {
        float x = cb[n] - mx, y = cb[NPT + n] - my, z = cb[2 * NPT + n] - mz;
        mn = fmaxf(mn, sqrtf(x * x + y * y + z * z));
    }
    mn = blockReduceMaxF(mn);
    if (threadIdx.x == 0) {
        cstat[b * 4 + 0] = mx;
        cstat[b * 4 + 1] = my;
        cstat[b * 4 + 2] = mz;
        cstat[b * 4 + 3] = 2.f * mn;
    }
}

// ---------------- 2. normalized coords + voxel idx + histogram + passthrough ---
__global__ void k_norm_idx(const float* __restrict__ coords, const float* __restrict__ cstat,
                           float* __restrict__ normc, int* __restrict__ vidx,
                           int* __restrict__ hist, float* __restrict__ out2) {
    int t = blockIdx.x * 256 + threadIdx.x;
    int b = t >> 15, n = t & 32767;
    float mx = cstat[b * 4 + 0], my = cstat[b * 4 + 1], mz = cstat[b * 4 + 2];
    float scale = cstat[b * 4 + 3];
    const float* cb = coords + (size_t)b * 3 * NPT;
    float x = cb[n], y = cb[NPT + n], z = cb[2 * NPT + n];
    float nx = fminf(fmaxf(((x - mx) / scale + 0.5f) * 32.f, 0.f), 31.f);
    float ny = fminf(fmaxf(((y - my) / scale + 0.5f) * 32.f, 0.f), 31.f);
    float nz = fminf(fmaxf(((z - mz) / scale + 0.5f) * 32.f, 0.f), 31.f);
    float* nb = normc + (size_t)b * 3 * NPT;
    nb[n] = nx; nb[NPT + n] = ny; nb[2 * NPT + n] = nz;
    int vx = (int)rintf(nx), vy = (int)rintf(ny), vz = (int)rintf(nz);
    int v = (vx * 32 + vy) * 32 + vz;
    vidx[t] = v;
    atomicAdd(&hist[(b << 15) + v], 1);
    float* o2 = out2 + (size_t)b * 3 * NPT;
    o2[n] = x; o2[NPT + n] = y; o2[2 * NPT + n] = z;
}

// ---------------- 3. per-batch exclusive prefix over 32768 bins ----------------
__global__ __launch_bounds__(1024) void k_prefix(const int* __restrict__ hist,
                                                 int* __restrict__ startB,
                                                 int* __restrict__ base) {
    int b = blockIdx.x;
    int tid = threadIdx.x;
    const int* h = hist + (b << 15);
    int loc[32];
    int s = 0;
    #pragma unroll
    for (int j = 0; j < 32; ++j) { loc[j] = h[tid * 32 + j]; s += loc[j]; }
    __shared__ int sm[1024];
    sm[tid] = s;
    __syncthreads();
    for (int o = 1; o < 1024; o <<= 1) {
        int v = (tid >= o) ? sm[tid - o] : 0;
        __syncthreads();
        sm[tid] += v;
        __syncthreads();
    }
    int run = (tid ? sm[tid - 1] : 0);
    #pragma unroll
    for (int j = 0; j < 32; ++j) {
        int idx = (b << 15) + tid * 32 + j;
        startB[idx] = run;
        base[idx] = run;
        run += loc[j];
    }
}

// ---------------- 4. reorder: feat [b][c][n] -> featT [b][slot][c] -------------
__global__ __launch_bounds__(256) void k_reorder(const float* __restrict__ feat,
                                                 const int* __restrict__ vidx,
                                                 int* __restrict__ base,
                                                 float* __restrict__ featT) {
    __shared__ float tile[64][65];
    __shared__ int sslot[64];
    int blk = blockIdx.x;             // 8192 = 16 b * 512
    int b = blk >> 9;
    int n0 = (blk & 511) << 6;
    int tid = threadIdx.x;
    const float* fb = feat + ((size_t)b << 21);
    for (int e = tid; e < 64 * 64; e += 256) {
        int c = e >> 6, nn = e & 63;
        tile[c][nn] = fb[((size_t)c << 15) + n0 + nn];
    }
    if (tid < 64) {
        int v = vidx[(b << 15) + n0 + tid];
        sslot[tid] = atomicAdd(&base[(b << 15) + v], 1);
    }
    __syncthreads();
    int p = tid >> 2, q = tid & 3;    // 4 threads/point, 16 ch each
    int slot = sslot[p];
    float* dst = featT + (((size_t)(b << 15) + slot) << 6) + q * 16;
    #pragma unroll
    for (int k = 0; k < 4; ++k) {
        float4 v4 = make_float4(tile[q * 16 + k * 4 + 0][p], tile[q * 16 + k * 4 + 1][p],
                                tile[q * 16 + k * 4 + 2][p], tile[q * 16 + k * 4 + 3][p]);
        *(float4*)(dst + k * 4) = v4;
    }
}

// ---------------- 5. voxel accumulate + divide + bf16 padded layout ------------
__global__ void k_vox_accum(const float* __restrict__ featT, const int* __restrict__ startB,
                            const int* __restrict__ base, short* __restrict__ vout) {
    int t = blockIdx.x * 256 + threadIdx.x;   // over B*R3*16
    int lane4 = t & 15;
    int v = (t >> 4) & 32767;
    int b = t >> 19;
    int start = startB[(b << 15) + v];
    int end   = base[(b << 15) + v];
    float4 acc = make_float4(0.f, 0.f, 0.f, 0.f);
    const float* fT = featT + (((size_t)b << 15) << 6) + lane4 * 4;
    for (int p = start; p < end; ++p) {
        const float4 f = *(const float4*)(fT + ((size_t)p << 6));
        acc.x += f.x; acc.y += f.y; acc.z += f.z; acc.w += f.w;
    }
    float rc = 1.f / fmaxf((float)(end - start), 1.f);
    short4 pk;
    pk.x = f2bf(acc.x * rc); pk.y = f2bf(acc.y * rc);
    pk.z = f2bf(acc.z * rc); pk.w = f2bf(acc.w * rc);
    *(short4*)(vout + (size_t)b * VOXB + ((size_t)(v >> 5) * 34 + (v & 31) + 1) * 64 + lane4 * 4) = pk;
}

// ---------------- 6. weight transpose: [co][ci][27] f32 -> [k][co][ci] bf16 ----
__global__ void k_wprep(const float* __restrict__ w, short* __restrict__ wT) {
    int e = blockIdx.x * 256 + threadIdx.x;   // 27*64*64 = 110592
    int ci = e & 63, co = (e >> 6) & 63, k = e >> 12;
    wT[e] = f2bf(w[(size_t)(co * 64 + ci) * 27 + k]);
}

// ---------------- 7. MFMA implicit-GEMM 3x3x3 conv -----------------------------
__global__ __launch_bounds__(256, 2) void k_conv_mfma(
    const short* __restrict__ vin, const short* __restrict__ wT,
    const float* __restrict__ bias, short* __restrict__ vout)
{
    int bid = blockIdx.x;                 // 1024 = 8 xcd * 2 b * 64 tiles
    int xcd = bid & 7, sub = bid >> 3;
    int b = (xcd << 1) | (sub >> 6);
    int tile = sub & 63;
    int x0 = (tile >> 3) << 2, y0 = (tile & 7) << 2;
    int tid = threadIdx.x;
    int wv = tid >> 6, l = tid & 63;
    int lo = l & 31, hi = l >> 5;
    int laneoff = lo * 64 + hi * 8;
    const short* vb = vin + (size_t)b * VOXB;

    f32x16 acc[2][4];
    #pragma unroll
    for (int cb = 0; cb < 2; ++cb)
        #pragma unroll
        for (int j = 0; j < 4; ++j)
            #pragma unroll
            for (int i = 0; i < 16; ++i) acc[cb][j][i] = 0.f;

    int xo = x0 + wv;   // this wave's output x line

    for (int tap = 0; tap < 27; ++tap) {
        int dx = tap / 9, dy = (tap / 3) % 3, dz = tap % 3;
        int xi = xo + dx - 1;
        if ((unsigned)xi >= 32u) continue;
        const short* wt = wT + tap * 4096 + laneoff;
        const short* lb[4];
        bool val[4];
        #pragma unroll
        for (int j = 0; j < 4; ++j) {
            int yi = y0 + j + dy - 1;
            val[j] = (unsigned)yi < 32u;
            lb[j] = vb + ((size_t)(xi * 32 + (yi & 31)) * 34 + dz) * 64 + laneoff;
        }
        #pragma unroll 2
        for (int cs = 0; cs < 4; ++cs) {
            bfx8 a0 = *(const bfx8*)(wt + cs * 16);
            bfx8 a1 = *(const bfx8*)(wt + 2048 + cs * 16);
            #pragma unroll
            for (int j = 0; j < 4; ++j) {
                if (!val[j]) continue;
                bfx8 bv = *(const bfx8*)(lb[j] + cs * 16);
                acc[0][j] = __builtin_amdgcn_mfma_f32_32x32x16_bf16(a0, bv, acc[0][j], 0, 0, 0);
                acc[1][j] = __builtin_amdgcn_mfma_f32_32x32x16_bf16(a1, bv, acc[1][j], 0, 0, 0);
            }
        }
    }

    short* ob = vout + (size_t)b * VOXB;
    #pragma unroll
    for (int cb = 0; cb < 2; ++cb) {
        #pragma unroll
        for (int j = 0; j < 4; ++j) {
            size_t rb = ((size_t)(xo * 32 + y0 + j) * 34 + 1 + lo) * 64;
            #pragma unroll
            for (int q = 0; q < 4; ++q) {
                int co0 = cb * 32 + hi * 4 + q * 8;
                short4 pk;
                pk.x = f2bf(acc[cb][j][q * 4 + 0] + bias[co0 + 0]);
                pk.y = f2bf(acc[cb][j][q * 4 + 1] + bias[co0 + 1]);
                pk.z = f2bf(acc[cb][j][q * 4 + 2] + bias[co0 + 2]);
                pk.w = f2bf(acc[cb][j][q * 4 + 3] + bias[co0 + 3]);
                *(short4*)(ob + rb + co0) = pk;
            }
        }
    }
}

// ---------------- 8. GN stats on padded bf16 volume (atomic partial sums) ------
__global__ void k_gn_stats_b(const short* __restrict__ v, float* __restrict__ st) {
    int b = blockIdx.x >> 3, p = blockIdx.x & 7;
    int tid = threadIdx.x;
    int cg = tid & 7, lv = tid >> 3;
    const short* vb = v + (size_t)b * VOXB + cg * 8;
    float s = 0.f, s2 = 0.f;
    for (int i = 0; i < 128; ++i) {
        int vx = p * 4096 + i * 32 + lv;
        usx8 hv = *(const usx8*)(vb + ((size_t)(vx >> 5) * 34 + (vx & 31) + 1) * 64);
        #pragma unroll
        for (int k = 0; k < 8; ++k) {
            float f = bf2f(hv[k]);
            s += f; s2 = fmaf(f, f, s2);
        }
    }
    #pragma unroll
    for (int o = 8; o < 64; o <<= 1) { s += __shfl_xor(s, o); s2 += __shfl_xor(s2, o); }
    __shared__ float sm[4][8][2];
    if ((tid & 63) < 8) { sm[tid >> 6][cg][0] = s; sm[tid >> 6][cg][1] = s2; }
    __syncthreads();
    if (tid < 8) {
        float a = 0.f, a2 = 0.f;
        #pragma unroll
        for (int w = 0; w < 4; ++w) { a += sm[w][tid][0]; a2 += sm[w][tid][1]; }
        atomicAdd(&st[(b * 8 + tid) * 2 + 0], a);
        atomicAdd(&st[(b * 8 + tid) * 2 + 1], a2);
    }
}

// ---------------- 9. GN apply + swish, in place on padded bf16 volume ----------
__global__ void k_gn_apply_b(short* __restrict__ v, const float* __restrict__ st,
                             const float* __restrict__ gamma, const float* __restrict__ beta) {
    int e = blockIdx.x * 256 + threadIdx.x;   // over 16*32768*8
    int cg = e & 7, vx = (e >> 3) & 32767, b = e >> 18;
    float s = st[(b * 8 + cg) * 2 + 0], s2 = st[(b * 8 + cg) * 2 + 1];
    float mean = s * (1.f / 262144.f);
    float var = s2 * (1.f / 262144.f) - mean * mean;
    float rstd = rsqrtf(var + 1e-5f);
    short* p = v + (size_t)b * VOXB + ((size_t)(vx >> 5) * 34 + (vx & 31) + 1) * 64 + cg * 8;
    usx8 hv = *(const usx8*)p;
    usx8 ov;
    #pragma unroll
    for (int i = 0; i < 8; ++i) {
        int co = cg * 8 + i;
        float f = bf2f(hv[i]);
        float g = (f - mean) * rstd * gamma[co] + beta[co];
        float sw = g / (1.f + __expf(-g));
        ov[i] = (unsigned short)f2bf(sw);
    }
    *(usx8*)p = ov;
}

// ---------------- 10. point branch GEMM: out1 = wp @ feat + bp -----------------
__global__ __launch_bounds__(256) void k_point(const float* __restrict__ feat,
                                               const float* __restrict__ wp,
                                               const float* __restrict__ bp,
                                               float* __restrict__ out1) {
    __shared__ float s_f[64][64];
    __shared__ float s_w[64][68];
    int nblk = blockIdx.x * 64;
    int b = blockIdx.y;
    int tid = threadIdx.x;
    const float* fb = feat + (((size_t)b * CCH) << 15);
    for (int e = tid; e < 64 * 64; e += 256) {
        int c = e >> 6, nn = e & 63;
        s_f[c][nn] = fb[(((size_t)c) << 15) + nblk + nn];
        s_w[nn][c] = wp[e];
    }
    __syncthreads();
    int o0 = (tid >> 4) << 2;
    int n0 = (tid & 15) << 2;
    float acc[4][4] = {{0.f}};
    for (int c = 0; c < 64; ++c) {
        float4 fv = *(const float4*)&s_f[c][n0];
        float4 wv = *(const float4*)&s_w[c][o0];
        float fvv[4] = {fv.x, fv.y, fv.z, fv.w};
        float wvv[4] = {wv.x, wv.y, wv.z, wv.w};
        #pragma unroll
        for (int j = 0; j < 4; ++j)
            #pragma unroll
            for (int i = 0; i < 4; ++i) acc[j][i] += wvv[j] * fvv[i];
    }
    #pragma unroll
    for (int j = 0; j < 4; ++j) {
        float bb = bp[o0 + j];
        float* op = out1 + (((size_t)(b * CCH + o0 + j)) << 15) + nblk + n0;
        float4 r = make_float4(acc[j][0] + bb, acc[j][1] + bb, acc[j][2] + bb, acc[j][3] + bb);
        *(float4*)op = r;
    }
}

// ---------------- 11. point-branch GN stats (f32, contiguous groups) -----------
__global__ void k_gn_stats_pt(const float* __restrict__ x, float* __restrict__ st) {
    int bg = blockIdx.x;
    const float* p = x + (size_t)bg * GSZ;
    float s = 0.f, s2 = 0.f;
    for (int i = threadIdx.x; i < GSZ; i += blockDim.x) {
        float v = p[i];
        s += v; s2 = fmaf(v, v, s2);
    }
    s  = blockReduceSumF(s);
    s2 = blockReduceSumF(s2);
    if (threadIdx.x == 0) {
        float mean = s / GSZ;
        float var = s2 / GSZ - mean * mean;
        st[bg * 2 + 0] = mean;
        st[bg * 2 + 1] = rsqrtf(var + 1e-5f);
    }
}

// ---------------- 12. final: devox gather + point GN/swish + add ---------------
__global__ void k_final(const short* __restrict__ h, const float* __restrict__ normc,
                        const float* __restrict__ stp, const float* __restrict__ gp,
                        const float* __restrict__ bep, float* __restrict__ out1) {
    int tid = threadIdx.x;
    int s = tid & 7, pp = tid >> 3;
    int pt = blockIdx.x * 32 + pp;
    int b = pt >> 15, n = pt & 32767;
    const float* nb = normc + (size_t)b * 3 * NPT;
    float nx = nb[n], ny = nb[NPT + n], nz = nb[2 * NPT + n];
    float fxf = floorf(nx), fyf = floorf(ny), fzf = floorf(nz);
    float fx = nx - fxf, fy = ny - fyf, fz = nz - fzf;
    int x0 = (int)fxf; x0 = x0 < 31 ? x0 : 31;
    int y0 = (int)fyf; y0 = y0 < 31 ? y0 : 31;
    int z0 = (int)fzf; z0 = z0 < 31 ? z0 : 31;
    int x1 = x0 + 1 < 31 ? x0 + 1 : 31;
    int y1 = y0 + 1 < 31 ? y0 + 1 : 31;
    int z1 = z0 + 1 < 31 ? z0 + 1 : 31;
    float wx0 = 1.f - fx, wx1 = fx, wy0 = 1.f - fy, wy1 = fy, wz0 = 1.f - fz, wz1 = fz;
    const short* hb = h + (size_t)b * VOXB + s * 8;
    float acc[8];
    #pragma unroll
    for (int i = 0; i < 8; ++i) acc[i] = 0.f;
    #pragma unroll
    for (int cx = 0; cx < 2; ++cx) {
        int xi = cx ? x1 : x0; float wxx = cx ? wx1 : wx0;
        #pragma unroll
        for (int cy = 0; cy < 2; ++cy) {
            int yi = cy ? y1 : y0; float wyy = cy ? wy1 : wy0;
            #pragma unroll
            for (int cz = 0; cz < 2; ++cz) {
                int zi = cz ? z1 : z0; float wzz = cz ? wz1 : wz0;
                float w = wxx * wyy * wzz;
                usx8 hv = *(const usx8*)(hb + ((size_t)(xi * 32 + yi) * 34 + zi + 1) * 64);
                #pragma unroll
                for (int i = 0; i < 8; ++i) acc[i] = fmaf(w, bf2f(hv[i]), acc[i]);
            }
        }
    }
    float mean = stp[(b * 8 + s) * 2 + 0], rstd = stp[(b * 8 + s) * 2 + 1];
    #pragma unroll
    for (int i = 0; i < 8; ++i) {
        int co = s * 8 + i;
        float* op = out1 + (((size_t)(b * CCH + co)) << 15) + n;
        float pv = *op;
        float g = (pv - mean) * rstd * gp[co] + bep[co];
        float sw = g / (1.f + __expf(-g));
        *op = acc[i] + sw;
    }
}

// --------------------------------- launcher ------------------------------------
extern "C" void kernel_launch(void* const* d_in, const int* in_sizes, int n_in,
                              void* d_out, int out_size, void* d_ws, size_t ws_size,
                              hipStream_t stream) {
    const float* feat   = (const float*)d_in[0];
    const float* coords = (const float*)d_in[1];
    const float* w1  = (const float*)d_in[2];
    const float* b1  = (const float*)d_in[3];
    const float* g1  = (const float*)d_in[4];
    const float* be1 = (const float*)d_in[5];
    const float* w2  = (const float*)d_in[6];
    const float* b2  = (const float*)d_in[7];
    const float* g2  = (const float*)d_in[8];
    const float* be2 = (const float*)d_in[9];
    const float* wp  = (const float*)d_in[10];
    const float* bp  = (const float*)d_in[11];
    const float* gp  = (const float*)d_in[12];
    const float* bep = (const float*)d_in[13];

    float* out1 = (float*)d_out;
    float* out2 = out1 + (size_t)BB * CCH * NPT;

    // workspace layout (~216 MB)
    const size_t featTBytes = (size_t)BB * NPT * CCH * 4;      // 134 MB, aliases voxT_mid
    float* featT    = (float*)d_ws;
    short* voxT_mid = (short*)d_ws;                            // alias (71 MB <= 134 MB)
    short* voxT_in  = (short*)((char*)d_ws + featTBytes);
    char* p = (char*)voxT_in + (size_t)BB * VOXB * 2;
    int*   hist   = (int*)p;  p += (size_t)BB * R3 * 4;
    int*   startB = (int*)p;  p += (size_t)BB * R3 * 4;
    int*   base   = (int*)p;  p += (size_t)BB * R3 * 4;
    float* normc = (float*)p; p += (size_t)BB * 3 * NPT * 4;
    int*   vidx  = (int*)p;   p += (size_t)BB * NPT * 4;
    float* cstat = (float*)p; p += 64 * 4;
    short* wT1   = (short*)p; p += 110592 * 2;
    short* wT2   = (short*)p; p += 110592 * 2;
    float* st1   = (float*)p; p += 256 * 4;
    float* st2   = (float*)p; p += 256 * 4;
    float* stp   = (float*)p; p += 256 * 4;

    hipMemsetAsync(voxT_in, 0, (size_t)BB * VOXB * 2, stream);
    hipMemsetAsync(hist, 0, (size_t)BB * R3 * 4, stream);
    hipMemsetAsync(st1, 0, 512 * 4, stream);   // st1 + st2 contiguous

    k_coord_stats<<<BB, 1024, 0, stream>>>(coords, cstat);
    k_norm_idx<<<(BB * NPT) / 256, 256, 0, stream>>>(coords, cstat, normc, vidx, hist, out2);
    k_prefix<<<BB, 1024, 0, stream>>>(hist, startB, base);
    k_reorder<<<(BB * NPT) / 64, 256, 0, stream>>>(feat, vidx, base, featT);
    k_vox_accum<<<(BB * R3 * 16) / 256, 256, 0, stream>>>(featT, startB, base, voxT_in);
    k_wprep<<<432, 256, 0, stream>>>(w1, wT1);
    k_wprep<<<432, 256, 0, stream>>>(w2, wT2);

    // featT no longer needed -> becomes voxT_mid (pads must be zero)
    hipMemsetAsync(voxT_mid, 0, (size_t)BB * VOXB * 2, stream);

    k_conv_mfma<<<1024, 256, 0, stream>>>(voxT_in, wT1, b1, voxT_mid);
    k_gn_stats_b<<<128, 256, 0, stream>>>(voxT_mid, st1);
    k_gn_apply_b<<<(BB * R3 * 8) / 256, 256, 0, stream>>>(voxT_mid, st1, g1, be1);

    k_conv_mfma<<<1024, 256, 0, stream>>>(voxT_mid, wT2, b2, voxT_in);  // voxT_in pads still zero
    k_gn_stats_b<<<128, 256, 0, stream>>>(voxT_in, st2);
    k_gn_apply_b<<<(BB * R3 * 8) / 256, 256, 0, stream>>>(voxT_in, st2, g2, be2);

    k_point<<<dim3(NPT / 64, BB), 256, 0, stream>>>(feat, wp, bp, out1);
    k_gn_stats_pt<<<128, 1024, 0, stream>>>(out1, stp);

    k_final<<<(BB * NPT) / 32, 256, 0, stream>>>(voxT_in, normc, stp, gp, bep, out1);
}

// Round 5
// 952.874 us; speedup vs baseline: 6.7389x; 1.4178x over previous
//
#include <hip/hip_runtime.h>
#include <hip/hip_bf16.h>
#include <math.h>

#define BB   16
#define CCH  64
#define NPT  32768
#define RR   32
#define R3   32768
#define GSZ  262144
#define VOXB 2228224   // 32*32*34*64 bf16 elements per batch (z padded to 34)

typedef __attribute__((ext_vector_type(8))) short bfx8;
typedef __attribute__((ext_vector_type(8))) unsigned short usx8;
typedef __attribute__((ext_vector_type(16))) float f32x16;

__device__ __forceinline__ short f2bf(float f) {
    unsigned u = __builtin_bit_cast(unsigned, f);
    u += 0x7fff + ((u >> 16) & 1);
    return (short)(u >> 16);
}
__device__ __forceinline__ float bf2f(unsigned short s) {
    unsigned u = ((unsigned)s) << 16;
    return __builtin_bit_cast(float, u);
}

// ---------------- block reduction helpers -------------------------------------
__device__ __forceinline__ float blockReduceSumF(float v) {
    __shared__ float sm[16];
    #pragma unroll
    for (int o = 32; o > 0; o >>= 1) v += __shfl_down(v, o);
    __syncthreads();
    if ((threadIdx.x & 63) == 0) sm[threadIdx.x >> 6] = v;
    __syncthreads();
    float s = 0.f;
    int nw = blockDim.x >> 6;
    for (int i = 0; i < nw; ++i) s += sm[i];
    return s;
}

__device__ __forceinline__ float blockReduceMaxF(float v) {
    __shared__ float sm[16];
    #pragma unroll
    for (int o = 32; o > 0; o >>= 1) v = fmaxf(v, __shfl_down(v, o));
    __syncthreads();
    if ((threadIdx.x & 63) == 0) sm[threadIdx.x >> 6] = v;
    __syncthreads();
    float s = sm[0];
    int nw = blockDim.x >> 6;
    for (int i = 1; i < nw; ++i) s = fmaxf(s, sm[i]);
    return s;
}

// ---------------- 1. per-batch coord stats ------------------------------------
__global__ __launch_bounds__(1024) void k_coord_stats(const float* __restrict__ coords,
                                                      float* __restrict__ cstat) {
    int b = blockIdx.x;
    const float* cb = coords + (size_t)b * 3 * NPT;
    float sx = 0.f, sy = 0.f, sz = 0.f;
    for (int n = threadIdx.x; n < NPT; n += 1024) {
        sx += cb[n]; sy += cb[NPT + n]; sz += cb[2 * NPT + n];
    }
    sx = blockReduceSumF(sx);
    sy = blockReduceSumF(sy);
    sz = blockReduceSumF(sz);
    float mx = sx / NPT, my = sy / NPT, mz = sz / NPT;
    float mn = 0.f;
    for (int n = threadIdx.x; n < NPT; n += 1024) {
        float x = cb[n] - mx, y = cb[NPT + n] - my, z = cb[2 * NPT + n] - mz;
        mn = fmaxf(mn, sqrtf(x * x + y * y + z * z));
    }
    mn = blockReduceMaxF(mn);
    if (threadIdx.x == 0) {
        cstat[b * 4 + 0] = mx;
        cstat[b * 4 + 1] = my;
        cstat[b * 4 + 2] = mz;
        cstat[b * 4 + 3] = 2.f * mn;
    }
}

// ---------------- 2. normalized coords + voxel idx + histogram + passthrough ---
__global__ void k_norm_idx(const float* __restrict__ coords, const float* __restrict__ cstat,
                           float* __restrict__ normc, int* __restrict__ vidx,
                           int* __restrict__ hist, float* __restrict__ out2) {
    int t = blockIdx.x * 256 + threadIdx.x;
    int b = t >> 15, n = t & 32767;
    float mx = cstat[b * 4 + 0], my = cstat[b * 4 + 1], mz = cstat[b * 4 + 2];
    float scale = cstat[b * 4 + 3];
    const float* cb = coords + (size_t)b * 3 * NPT;
    float x = cb[n], y = cb[NPT + n], z = cb[2 * NPT + n];
    float nx = fminf(fmaxf(((x - mx) / scale + 0.5f) * 32.f, 0.f), 31.f);
    float ny = fminf(fmaxf(((y - my) / scale + 0.5f) * 32.f, 0.f), 31.f);
    float nz = fminf(fmaxf(((z - mz) / scale + 0.5f) * 32.f, 0.f), 31.f);
    float* nb = normc + (size_t)b * 3 * NPT;
    nb[n] = nx; nb[NPT + n] = ny; nb[2 * NPT + n] = nz;
    int vx = (int)rintf(nx), vy = (int)rintf(ny), vz = (int)rintf(nz);
    int v = (vx * 32 + vy) * 32 + vz;
    vidx[t] = v;
    atomicAdd(&hist[(b << 15) + v], 1);
    float* o2 = out2 + (size_t)b * 3 * NPT;
    o2[n] = x; o2[NPT + n] = y; o2[2 * NPT + n] = z;
}

// ---------------- 3. per-batch exclusive prefix over 32768 bins ----------------
__global__ __launch_bounds__(1024) void k_prefix(const int* __restrict__ hist,
                                                 int* __restrict__ startB,
                                                 int* __restrict__ base) {
    int b = blockIdx.x;
    int tid = threadIdx.x;
    const int* h = hist + (b << 15);
    int loc[32];
    int s = 0;
    #pragma unroll
    for (int j = 0; j < 32; ++j) { loc[j] = h[tid * 32 + j]; s += loc[j]; }
    __shared__ int sm[1024];
    sm[tid] = s;
    __syncthreads();
    for (int o = 1; o < 1024; o <<= 1) {
        int v = (tid >= o) ? sm[tid - o] : 0;
        __syncthreads();
        sm[tid] += v;
        __syncthreads();
    }
    int run = (tid ? sm[tid - 1] : 0);
    #pragma unroll
    for (int j = 0; j < 32; ++j) {
        int idx = (b << 15) + tid * 32 + j;
        startB[idx] = run;
        base[idx] = run;
        run += loc[j];
    }
}

// ---------------- 4. reorder: feat [b][c][n] -> featT [b][slot][c] -------------
__global__ __launch_bounds__(256) void k_reorder(const float* __restrict__ feat,
                                                 const int* __restrict__ vidx,
                                                 int* __restrict__ base,
                                                 float* __restrict__ featT) {
    __shared__ float tile[64][65];
    __shared__ int sslot[64];
    int blk = blockIdx.x;             // 8192 = 16 b * 512
    int b = blk >> 9;
    int n0 = (blk & 511) << 6;
    int tid = threadIdx.x;
    const float* fb = feat + ((size_t)b << 21);
    for (int e = tid; e < 64 * 64; e += 256) {
        int c = e >> 6, nn = e & 63;
        tile[c][nn] = fb[((size_t)c << 15) + n0 + nn];
    }
    if (tid < 64) {
        int v = vidx[(b << 15) + n0 + tid];
        sslot[tid] = atomicAdd(&base[(b << 15) + v], 1);
    }
    __syncthreads();
    int p = tid >> 2, q = tid & 3;    // 4 threads/point, 16 ch each
    int slot = sslot[p];
    float* dst = featT + (((size_t)(b << 15) + slot) << 6) + q * 16;
    #pragma unroll
    for (int k = 0; k < 4; ++k) {
        float4 v4 = make_float4(tile[q * 16 + k * 4 + 0][p], tile[q * 16 + k * 4 + 1][p],
                                tile[q * 16 + k * 4 + 2][p], tile[q * 16 + k * 4 + 3][p]);
        *(float4*)(dst + k * 4) = v4;
    }
}

// ---------------- 5. voxel accumulate + divide + bf16 padded layout ------------
__global__ void k_vox_accum(const float* __restrict__ featT, const int* __restrict__ startB,
                            const int* __restrict__ base, short* __restrict__ vout) {
    int t = blockIdx.x * 256 + threadIdx.x;   // over B*R3*16
    int lane4 = t & 15;
    int v = (t >> 4) & 32767;
    int b = t >> 19;
    int start = startB[(b << 15) + v];
    int end   = base[(b << 15) + v];
    float4 acc = make_float4(0.f, 0.f, 0.f, 0.f);
    const float* fT = featT + (((size_t)b << 15) << 6) + lane4 * 4;
    for (int p = start; p < end; ++p) {
        const float4 f = *(const float4*)(fT + ((size_t)p << 6));
        acc.x += f.x; acc.y += f.y; acc.z += f.z; acc.w += f.w;
    }
    float rc = 1.f / fmaxf((float)(end - start), 1.f);
    short4 pk;
    pk.x = f2bf(acc.x * rc); pk.y = f2bf(acc.y * rc);
    pk.z = f2bf(acc.z * rc); pk.w = f2bf(acc.w * rc);
    *(short4*)(vout + (size_t)b * VOXB + ((size_t)(v >> 5) * 34 + (v & 31) + 1) * 64 + lane4 * 4) = pk;
}

// ---------------- 6. weight transpose: [co][ci][27] f32 -> [k][co][ci] bf16 ----
__global__ void k_wprep(const float* __restrict__ w, short* __restrict__ wT) {
    int e = blockIdx.x * 256 + threadIdx.x;   // 27*64*64 = 110592
    int ci = e & 63, co = (e >> 6) & 63, k = e >> 12;
    wT[e] = f2bf(w[(size_t)(co * 64 + ci) * 27 + k]);
}

// ---------------- 7. MFMA implicit-GEMM 3x3x3 conv, LDS-staged -----------------
// Per block: output tile 4x * 4y * 32z * 64co. 4 waves, wave wv owns x-line x0+wv.
// Loop h over 2 ci-halves: stage 6x*6y*34z*32ci halo region into LDS (76.5 KB)
// with 16B-slot XOR swizzle ((z&3)<<4 bytes) to kill bank conflicts, then 27 taps
// * 2 cs * 4 j * 2 co-halves of mfma_32x32x16_bf16. OOB halo lines zero-filled,
// no validity branches. Weights prefetched one tap ahead from L2-hot wT.
__global__ __launch_bounds__(256, 2) void k_conv_mfma(
    const short* __restrict__ vin, const short* __restrict__ wT,
    const float* __restrict__ bias, short* __restrict__ vout)
{
    __shared__ short lds[36 * 1088];      // 36 lines * 34 z * 32 ci = 78336 B
    int bid = blockIdx.x;                 // 1024 = 8 xcd * 2 b * 64 tiles
    int xcd = bid & 7, sub = bid >> 3;
    int b = (xcd << 1) | (sub >> 6);
    int tile = sub & 63;
    int x0 = (tile >> 3) << 2, y0 = (tile & 7) << 2;
    int tid = threadIdx.x;
    int wv = tid >> 6, l = tid & 63;
    int lo = l & 31, hi = l >> 5;
    const short* vb = vin + (size_t)b * VOXB;
    int xo = x0 + wv;

    f32x16 acc[2][4];
    #pragma unroll
    for (int cb = 0; cb < 2; ++cb)
        #pragma unroll
        for (int j = 0; j < 4; ++j)
            #pragma unroll
            for (int i = 0; i < 16; ++i) acc[cb][j][i] = 0.f;

    for (int h = 0; h < 2; ++h) {
        if (h) __syncthreads();           // finish reads of previous half
        // ---- stage 36 lines * 34 z * 4 chunks(16B) = 4896 chunks ----
        for (int e = tid; e < 4896; e += 256) {
            int line = e / 136, r = e - line * 136;
            int z = r >> 2, q = r & 3;
            int xx = line / 6, yy = line - xx * 6;
            int xi = x0 + xx - 1, yi = y0 + yy - 1;
            int4 v = make_int4(0, 0, 0, 0);
            if ((unsigned)xi < 32u && (unsigned)yi < 32u)
                v = *(const int4*)(vb + ((size_t)(xi * 32 + yi) * 34 + z) * 64 + h * 32 + q * 8);
            int dst = line * 1088 + z * 32 + ((q * 8) ^ ((z & 3) << 3));   // shorts
            *(int4*)(lds + dst) = v;
        }
        __syncthreads();
        // ---- compute: 27 taps ----
        const short* whb = wT + h * 32 + lo * 64 + hi * 8;
        bfx8 acur0, acur1, acur2, acur3, anx0, anx1, anx2, anx3;
        {
            const short* wt = whb;
            acur0 = *(const bfx8*)(wt);
            acur1 = *(const bfx8*)(wt + 2048);
            acur2 = *(const bfx8*)(wt + 16);
            acur3 = *(const bfx8*)(wt + 2048 + 16);
        }
        for (int tap = 0; tap < 27; ++tap) {
            if (tap < 26) {
                const short* wt = whb + (tap + 1) * 4096;
                anx0 = *(const bfx8*)(wt);
                anx1 = *(const bfx8*)(wt + 2048);
                anx2 = *(const bfx8*)(wt + 16);
                anx3 = *(const bfx8*)(wt + 2048 + 16);
            }
            int dx = tap / 9, dy = (tap / 3) % 3, dz = tap % 3;
            int zz = dz + lo;
            int so = (zz & 3) << 3;                   // slot swizzle (shorts)
            int s0 = (hi * 8) ^ so;
            int s1 = (16 + hi * 8) ^ so;
            const short* bbase = lds + ((wv + dx) * 6 + dy) * 1088 + zz * 32;
            #pragma unroll
            for (int j = 0; j < 4; ++j) {
                const short* bp = bbase + j * 1088;
                bfx8 b0 = *(const bfx8*)(bp + s0);
                bfx8 b1 = *(const bfx8*)(bp + s1);
                acc[0][j] = __builtin_amdgcn_mfma_f32_32x32x16_bf16(acur0, b0, acc[0][j], 0, 0, 0);
                acc[1][j] = __builtin_amdgcn_mfma_f32_32x32x16_bf16(acur1, b0, acc[1][j], 0, 0, 0);
                acc[0][j] = __builtin_amdgcn_mfma_f32_32x32x16_bf16(acur2, b1, acc[0][j], 0, 0, 0);
                acc[1][j] = __builtin_amdgcn_mfma_f32_32x32x16_bf16(acur3, b1, acc[1][j], 0, 0, 0);
            }
            acur0 = anx0; acur1 = anx1; acur2 = anx2; acur3 = anx3;
        }
    }

    short* ob = vout + (size_t)b * VOXB;
    #pragma unroll
    for (int cb = 0; cb < 2; ++cb) {
        #pragma unroll
        for (int j = 0; j < 4; ++j) {
            size_t rb = ((size_t)(xo * 32 + y0 + j) * 34 + 1 + lo) * 64;
            #pragma unroll
            for (int q = 0; q < 4; ++q) {
                int co0 = cb * 32 + hi * 4 + q * 8;
                short4 pk;
                pk.x = f2bf(acc[cb][j][q * 4 + 0] + bias[co0 + 0]);
                pk.y = f2bf(acc[cb][j][q * 4 + 1] + bias[co0 + 1]);
                pk.z = f2bf(acc[cb][j][q * 4 + 2] + bias[co0 + 2]);
                pk.w = f2bf(acc[cb][j][q * 4 + 3] + bias[co0 + 3]);
                *(short4*)(ob + rb + co0) = pk;
            }
        }
    }
}

// ---------------- 8. GN stats on padded bf16 volume (atomic partial sums) ------
__global__ void k_gn_stats_b(const short* __restrict__ v, float* __restrict__ st) {
    int b = blockIdx.x >> 3, p = blockIdx.x & 7;
    int tid = threadIdx.x;
    int cg = tid & 7, lv = tid >> 3;
    const short* vb = v + (size_t)b * VOXB + cg * 8;
    float s = 0.f, s2 = 0.f;
    for (int i = 0; i < 128; ++i) {
        int vx = p * 4096 + i * 32 + lv;
        usx8 hv = *(const usx8*)(vb + ((size_t)(vx >> 5) * 34 + (vx & 31) + 1) * 64);
        #pragma unroll
        for (int k = 0; k < 8; ++k) {
            float f = bf2f(hv[k]);
            s += f; s2 = fmaf(f, f, s2);
        }
    }
    #pragma unroll
    for (int o = 8; o < 64; o <<= 1) { s += __shfl_xor(s, o); s2 += __shfl_xor(s2, o); }
    __shared__ float sm[4][8][2];
    if ((tid & 63) < 8) { sm[tid >> 6][cg][0] = s; sm[tid >> 6][cg][1] = s2; }
    __syncthreads();
    if (tid < 8) {
        float a = 0.f, a2 = 0.f;
        #pragma unroll
        for (int w = 0; w < 4; ++w) { a += sm[w][tid][0]; a2 += sm[w][tid][1]; }
        atomicAdd(&st[(b * 8 + tid) * 2 + 0], a);
        atomicAdd(&st[(b * 8 + tid) * 2 + 1], a2);
    }
}

// ---------------- 9. GN apply + swish, in place on padded bf16 volume ----------
__global__ void k_gn_apply_b(short* __restrict__ v, const float* __restrict__ st,
                             const float* __restrict__ gamma, const float* __restrict__ beta) {
    int e = blockIdx.x * 256 + threadIdx.x;   // over 16*32768*8
    int cg = e & 7, vx = (e >> 3) & 32767, b = e >> 18;
    float s = st[(b * 8 + cg) * 2 + 0], s2 = st[(b * 8 + cg) * 2 + 1];
    float mean = s * (1.f / 262144.f);
    float var = s2 * (1.f / 262144.f) - mean * mean;
    float rstd = rsqrtf(var + 1e-5f);
    short* p = v + (size_t)b * VOXB + ((size_t)(vx >> 5) * 34 + (vx & 31) + 1) * 64 + cg * 8;
    usx8 hv = *(const usx8*)p;
    usx8 ov;
    #pragma unroll
    for (int i = 0; i < 8; ++i) {
        int co = cg * 8 + i;
        float f = bf2f(hv[i]);
        float g = (f - mean) * rstd * gamma[co] + beta[co];
        float sw = g / (1.f + __expf(-g));
        ov[i] = (unsigned short)f2bf(sw);
    }
    *(usx8*)p = ov;
}

// ---------------- 10. point branch GEMM: out1 = wp @ feat + bp -----------------
__global__ __launch_bounds__(256) void k_point(const float* __restrict__ feat,
                                               const float* __restrict__ wp,
                                               const float* __restrict__ bp,
                                               float* __restrict__ out1) {
    __shared__ float s_f[64][64];
    __shared__ float s_w[64][68];
    int nblk = blockIdx.x * 64;
    int b = blockIdx.y;
    int tid = threadIdx.x;
    const float* fb = feat + (((size_t)b * CCH) << 15);
    for (int e = tid; e < 64 * 64; e += 256) {
        int c = e >> 6, nn = e & 63;
        s_f[c][nn] = fb[(((size_t)c) << 15) + nblk + nn];
        s_w[nn][c] = wp[e];
    }
    __syncthreads();
    int o0 = (tid >> 4) << 2;
    int n0 = (tid & 15) << 2;
    float acc[4][4] = {{0.f}};
    for (int c = 0; c < 64; ++c) {
        float4 fv = *(const float4*)&s_f[c][n0];
        float4 wv = *(const float4*)&s_w[c][o0];
        float fvv[4] = {fv.x, fv.y, fv.z, fv.w};
        float wvv[4] = {wv.x, wv.y, wv.z, wv.w};
        #pragma unroll
        for (int j = 0; j < 4; ++j)
            #pragma unroll
            for (int i = 0; i < 4; ++i) acc[j][i] += wvv[j] * fvv[i];
    }
    #pragma unroll
    for (int j = 0; j < 4; ++j) {
        float bb = bp[o0 + j];
        float* op = out1 + (((size_t)(b * CCH + o0 + j)) << 15) + nblk + n0;
        float4 r = make_float4(acc[j][0] + bb, acc[j][1] + bb, acc[j][2] + bb, acc[j][3] + bb);
        *(float4*)op = r;
    }
}

// ---------------- 11. point-branch GN stats (f32, contiguous groups) -----------
__global__ void k_gn_stats_pt(const float* __restrict__ x, float* __restrict__ st) {
    int bg = blockIdx.x;
    const float* p = x + (size_t)bg * GSZ;
    float s = 0.f, s2 = 0.f;
    for (int i = threadIdx.x; i < GSZ; i += blockDim.x) {
        float v = p[i];
        s += v; s2 = fmaf(v, v, s2);
    }
    s  = blockReduceSumF(s);
    s2 = blockReduceSumF(s2);
    if (threadIdx.x == 0) {
        float mean = s / GSZ;
        float var = s2 / GSZ - mean * mean;
        st[bg * 2 + 0] = mean;
        st[bg * 2 + 1] = rsqrtf(var + 1e-5f);
    }
}

// ---------------- 12. final: devox gather + point GN/swish + add ---------------
__global__ void k_final(const short* __restrict__ h, const float* __restrict__ normc,
                        const float* __restrict__ stp, const float* __restrict__ gp,
                        const float* __restrict__ bep, float* __restrict__ out1) {
    int tid = threadIdx.x;
    int s = tid & 7, pp = tid >> 3;
    int pt = blockIdx.x * 32 + pp;
    int b = pt >> 15, n = pt & 32767;
    const float* nb = normc + (size_t)b * 3 * NPT;
    float nx = nb[n], ny = nb[NPT + n], nz = nb[2 * NPT + n];
    float fxf = floorf(nx), fyf = floorf(ny), fzf = floorf(nz);
    float fx = nx - fxf, fy = ny - fyf, fz = nz - fzf;
    int x0 = (int)fxf; x0 = x0 < 31 ? x0 : 31;
    int y0 = (int)fyf; y0 = y0 < 31 ? y0 : 31;
    int z0 = (int)fzf; z0 = z0 < 31 ? z0 : 31;
    int x1 = x0 + 1 < 31 ? x0 + 1 : 31;
    int y1 = y0 + 1 < 31 ? y0 + 1 : 31;
    int z1 = z0 + 1 < 31 ? z0 + 1 : 31;
    float wx0 = 1.f - fx, wx1 = fx, wy0 = 1.f - fy, wy1 = fy, wz0 = 1.f - fz, wz1 = fz;
    const short* hb = h + (size_t)b * VOXB + s * 8;
    float acc[8];
    #pragma unroll
    for (int i = 0; i < 8; ++i) acc[i] = 0.f;
    #pragma unroll
    for (int cx = 0; cx < 2; ++cx) {
        int xi = cx ? x1 : x0; float wxx = cx ? wx1 : wx0;
        #pragma unroll
        for (int cy = 0; cy < 2; ++cy) {
            int yi = cy ? y1 : y0; float wyy = cy ? wy1 : wy0;
            #pragma unroll
            for (int cz = 0; cz < 2; ++cz) {
                int zi = cz ? z1 : z0; float wzz = cz ? wz1 : wz0;
                float w = wxx * wyy * wzz;
                usx8 hv = *(const usx8*)(hb + ((size_t)(xi * 32 + yi) * 34 + zi + 1) * 64);
                #pragma unroll
                for (int i = 0; i < 8; ++i) acc[i] = fmaf(w, bf2f(hv[i]), acc[i]);
            }
        }
    }
    float mean = stp[(b * 8 + s) * 2 + 0], rstd = stp[(b * 8 + s) * 2 + 1];
    #pragma unroll
    for (int i = 0; i < 8; ++i) {
        int co = s * 8 + i;
        float* op = out1 + (((size_t)(b * CCH + co)) << 15) + n;
        float pv = *op;
        float g = (pv - mean) * rstd * gp[co] + bep[co];
        float sw = g / (1.f + __expf(-g));
        *op = acc[i] + sw;
    }
}

// --------------------------------- launcher ------------------------------------
extern "C" void kernel_launch(void* const* d_in, const int* in_sizes, int n_in,
                              void* d_out, int out_size, void* d_ws, size_t ws_size,
                              hipStream_t stream) {
    const float* feat   = (const float*)d_in[0];
    const float* coords = (const float*)d_in[1];
    const float* w1  = (const float*)d_in[2];
    const float* b1  = (const float*)d_in[3];
    const float* g1  = (const float*)d_in[4];
    const float* be1 = (const float*)d_in[5];
    const float* w2  = (const float*)d_in[6];
    const float* b2  = (const float*)d_in[7];
    const float* g2  = (const float*)d_in[8];
    const float* be2 = (const float*)d_in[9];
    const float* wp  = (const float*)d_in[10];
    const float* bp  = (const float*)d_in[11];
    const float* gp  = (const float*)d_in[12];
    const float* bep = (const float*)d_in[13];

    float* out1 = (float*)d_out;
    float* out2 = out1 + (size_t)BB * CCH * NPT;

    // workspace layout (~216 MB)
    const size_t featTBytes = (size_t)BB * NPT * CCH * 4;      // 134 MB, aliases voxT_mid
    float* featT    = (float*)d_ws;
    short* voxT_mid = (short*)d_ws;                            // alias (71 MB <= 134 MB)
    short* voxT_in  = (short*)((char*)d_ws + featTBytes);
    char* p = (char*)voxT_in + (size_t)BB * VOXB * 2;
    int*   hist   = (int*)p;  p += (size_t)BB * R3 * 4;
    int*   startB = (int*)p;  p += (size_t)BB * R3 * 4;
    int*   base   = (int*)p;  p += (size_t)BB * R3 * 4;
    float* normc = (float*)p; p += (size_t)BB * 3 * NPT * 4;
    int*   vidx  = (int*)p;   p += (size_t)BB * NPT * 4;
    float* cstat = (float*)p; p += 64 * 4;
    short* wT1   = (short*)p; p += 110592 * 2;
    short* wT2   = (short*)p; p += 110592 * 2;
    float* st1   = (float*)p; p += 256 * 4;
    float* st2   = (float*)p; p += 256 * 4;
    float* stp   = (float*)p; p += 256 * 4;

    hipMemsetAsync(voxT_in, 0, (size_t)BB * VOXB * 2, stream);
    hipMemsetAsync(hist, 0, (size_t)BB * R3 * 4, stream);
    hipMemsetAsync(st1, 0, 512 * 4, stream);   // st1 + st2 contiguous

    k_coord_stats<<<BB, 1024, 0, stream>>>(coords, cstat);
    k_norm_idx<<<(BB * NPT) / 256, 256, 0, stream>>>(coords, cstat, normc, vidx, hist, out2);
    k_prefix<<<BB, 1024, 0, stream>>>(hist, startB, base);
    k_reorder<<<(BB * NPT) / 64, 256, 0, stream>>>(feat, vidx, base, featT);
    k_vox_accum<<<(BB * R3 * 16) / 256, 256, 0, stream>>>(featT, startB, base, voxT_in);
    k_wprep<<<432, 256, 0, stream>>>(w1, wT1);
    k_wprep<<<432, 256, 0, stream>>>(w2, wT2);

    // featT no longer needed -> becomes voxT_mid (pads must be zero)
    hipMemsetAsync(voxT_mid, 0, (size_t)BB * VOXB * 2, stream);

    k_conv_mfma<<<1024, 256, 0, stream>>>(voxT_in, wT1, b1, voxT_mid);
    k_gn_stats_b<<<128, 256, 0, stream>>>(voxT_mid, st1);
    k_gn_apply_b<<<(BB * R3 * 8) / 256, 256, 0, stream>>>(voxT_mid, st1, g1, be1);

    k_conv_mfma<<<1024, 256, 0, stream>>>(voxT_mid, wT2, b2, voxT_in);  // voxT_in pads still zero
    k_gn_stats_b<<<128, 256, 0, stream>>>(voxT_in, st2);
    k_gn_apply_b<<<(BB * R3 * 8) / 256, 256, 0, stream>>>(voxT_in, st2, g2, be2);

    k_point<<<dim3(NPT / 64, BB), 256, 0, stream>>>(feat, wp, bp, out1);
    k_gn_stats_pt<<<128, 1024, 0, stream>>>(out1, stp);

    k_final<<<(BB * NPT) / 32, 256, 0, stream>>>(voxT_in, normc, stp, gp, bep, out1);
}

// Round 6
// 757.332 us; speedup vs baseline: 8.4788x; 1.2582x over previous
//
#include <hip/hip_runtime.h>
#include <hip/hip_bf16.h>
#include <math.h>

#define BB   16
#define CCH  64
#define NPT  32768
#define RR   32
#define R3   32768
#define GSZ  262144
#define VOXB 2228224   // 32*32*34*64 bf16 elements per batch (z padded to 34)

typedef __attribute__((ext_vector_type(8))) short bfx8;
typedef __attribute__((ext_vector_type(8))) unsigned short usx8;
typedef __attribute__((ext_vector_type(16))) float f32x16;

__device__ __forceinline__ short f2bf(float f) {
    unsigned u = __builtin_bit_cast(unsigned, f);
    u += 0x7fff + ((u >> 16) & 1);
    return (short)(u >> 16);
}
__device__ __forceinline__ float bf2f(unsigned short s) {
    unsigned u = ((unsigned)s) << 16;
    return __builtin_bit_cast(float, u);
}

// ---------------- block reduction helpers -------------------------------------
__device__ __forceinline__ float blockReduceSumF(float v) {
    __shared__ float sm[16];
    #pragma unroll
    for (int o = 32; o > 0; o >>= 1) v += __shfl_down(v, o);
    __syncthreads();
    if ((threadIdx.x & 63) == 0) sm[threadIdx.x >> 6] = v;
    __syncthreads();
    float s = 0.f;
    int nw = blockDim.x >> 6;
    for (int i = 0; i < nw; ++i) s += sm[i];
    return s;
}

__device__ __forceinline__ float blockReduceMaxF(float v) {
    __shared__ float sm[16];
    #pragma unroll
    for (int o = 32; o > 0; o >>= 1) v = fmaxf(v, __shfl_down(v, o));
    __syncthreads();
    if ((threadIdx.x & 63) == 0) sm[threadIdx.x >> 6] = v;
    __syncthreads();
    float s = sm[0];
    int nw = blockDim.x >> 6;
    for (int i = 1; i < nw; ++i) s = fmaxf(s, sm[i]);
    return s;
}

// ---------------- 1a. coord partial sums (128 blocks) --------------------------
__global__ void k_cstat_sum(const float* __restrict__ coords, float* __restrict__ csum) {
    int b = blockIdx.x >> 3, seg = blockIdx.x & 7;
    const float* cb = coords + (size_t)b * 3 * NPT;
    int n0 = seg << 12;
    float sx = 0.f, sy = 0.f, sz = 0.f;
    for (int n = n0 + threadIdx.x; n < n0 + 4096; n += 256) {
        sx += cb[n]; sy += cb[NPT + n]; sz += cb[2 * NPT + n];
    }
    sx = blockReduceSumF(sx);
    sy = blockReduceSumF(sy);
    sz = blockReduceSumF(sz);
    if (threadIdx.x == 0) {
        atomicAdd(&csum[b * 4 + 0], sx);
        atomicAdd(&csum[b * 4 + 1], sy);
        atomicAdd(&csum[b * 4 + 2], sz);
    }
}

// ---------------- 1b. coord max distance (128 blocks, int-bits atomicMax) ------
__global__ void k_cstat_max(const float* __restrict__ coords, const float* __restrict__ csum,
                            int* __restrict__ cmax) {
    int b = blockIdx.x >> 3, seg = blockIdx.x & 7;
    const float* cb = coords + (size_t)b * 3 * NPT;
    float mx = csum[b * 4 + 0] * (1.f / NPT);
    float my = csum[b * 4 + 1] * (1.f / NPT);
    float mz = csum[b * 4 + 2] * (1.f / NPT);
    int n0 = seg << 12;
    float mn = 0.f;
    for (int n = n0 + threadIdx.x; n < n0 + 4096; n += 256) {
        float x = cb[n] - mx, y = cb[NPT + n] - my, z = cb[2 * NPT + n] - mz;
        mn = fmaxf(mn, sqrtf(x * x + y * y + z * z));
    }
    mn = blockReduceMaxF(mn);
    if (threadIdx.x == 0) atomicMax(&cmax[b], __float_as_int(mn));
}

// ---------------- 2. normalized coords + voxel idx + histogram + passthrough ---
__global__ void k_norm_idx(const float* __restrict__ coords, const float* __restrict__ csum,
                           const int* __restrict__ cmax,
                           float* __restrict__ normc, int* __restrict__ vidx,
                           int* __restrict__ hist, float* __restrict__ out2) {
    int t = blockIdx.x * 256 + threadIdx.x;
    int b = t >> 15, n = t & 32767;
    float mx = csum[b * 4 + 0] * (1.f / NPT);
    float my = csum[b * 4 + 1] * (1.f / NPT);
    float mz = csum[b * 4 + 2] * (1.f / NPT);
    float scale = 2.f * __int_as_float(cmax[b]);
    const float* cb = coords + (size_t)b * 3 * NPT;
    float x = cb[n], y = cb[NPT + n], z = cb[2 * NPT + n];
    float nx = fminf(fmaxf(((x - mx) / scale + 0.5f) * 32.f, 0.f), 31.f);
    float ny = fminf(fmaxf(((y - my) / scale + 0.5f) * 32.f, 0.f), 31.f);
    float nz = fminf(fmaxf(((z - mz) / scale + 0.5f) * 32.f, 0.f), 31.f);
    float* nb = normc + (size_t)b * 3 * NPT;
    nb[n] = nx; nb[NPT + n] = ny; nb[2 * NPT + n] = nz;
    int vx = (int)rintf(nx), vy = (int)rintf(ny), vz = (int)rintf(nz);
    int v = (vx * 32 + vy) * 32 + vz;
    vidx[t] = v;
    atomicAdd(&hist[(b << 15) + v], 1);
    float* o2 = out2 + (size_t)b * 3 * NPT;
    o2[n] = x; o2[NPT + n] = y; o2[2 * NPT + n] = z;
}

// ---------------- 3. per-batch exclusive prefix over 32768 bins ----------------
__global__ __launch_bounds__(1024) void k_prefix(const int* __restrict__ hist,
                                                 int* __restrict__ startB,
                                                 int* __restrict__ base) {
    int b = blockIdx.x;
    int tid = threadIdx.x;
    const int* h = hist + (b << 15);
    int loc[32];
    int s = 0;
    #pragma unroll
    for (int j = 0; j < 32; ++j) { loc[j] = h[tid * 32 + j]; s += loc[j]; }
    __shared__ int sm[1024];
    sm[tid] = s;
    __syncthreads();
    for (int o = 1; o < 1024; o <<= 1) {
        int v = (tid >= o) ? sm[tid - o] : 0;
        __syncthreads();
        sm[tid] += v;
        __syncthreads();
    }
    int run = (tid ? sm[tid - 1] : 0);
    #pragma unroll
    for (int j = 0; j < 32; ++j) {
        int idx = (b << 15) + tid * 32 + j;
        startB[idx] = run;
        base[idx] = run;
        run += loc[j];
    }
}

// ---------------- 4. reorder: feat [b][c][n] f32 -> featT [b][slot][c] bf16 ----
__global__ __launch_bounds__(256) void k_reorder(const float* __restrict__ feat,
                                                 const int* __restrict__ vidx,
                                                 int* __restrict__ base,
                                                 short* __restrict__ featT) {
    __shared__ float tile[64][65];
    __shared__ int sslot[64];
    int blk = blockIdx.x;             // 8192 = 16 b * 512
    int b = blk >> 9;
    int n0 = (blk & 511) << 6;
    int tid = threadIdx.x;
    const float* fb = feat + ((size_t)b << 21);
    for (int e = tid; e < 64 * 64; e += 256) {
        int c = e >> 6, nn = e & 63;
        tile[c][nn] = fb[((size_t)c << 15) + n0 + nn];
    }
    if (tid < 64) {
        int v = vidx[(b << 15) + n0 + tid];
        sslot[tid] = atomicAdd(&base[(b << 15) + v], 1);
    }
    __syncthreads();
    int p = tid >> 2, q = tid & 3;    // 4 threads/point, 16 ch each
    int slot = sslot[p];
    short* dst = featT + (((size_t)((b << 15) + slot)) << 6) + q * 16;
    unsigned pk[8];
    #pragma unroll
    for (int k = 0; k < 8; ++k) {
        unsigned lo16 = (unsigned short)f2bf(tile[q * 16 + 2 * k][p]);
        unsigned hi16 = (unsigned short)f2bf(tile[q * 16 + 2 * k + 1][p]);
        pk[k] = lo16 | (hi16 << 16);
    }
    *(int4*)dst = make_int4(pk[0], pk[1], pk[2], pk[3]);
    *(int4*)(dst + 8) = make_int4(pk[4], pk[5], pk[6], pk[7]);
}

// ---------------- 5. voxel accumulate + divide + bf16 padded layout ------------
__global__ void k_vox_accum(const short* __restrict__ featT, const int* __restrict__ startB,
                            const int* __restrict__ base, short* __restrict__ vout) {
    int t = blockIdx.x * 256 + threadIdx.x;   // over B*R3*16
    int lane4 = t & 15;
    int v = (t >> 4) & 32767;
    int b = t >> 19;
    int start = startB[(b << 15) + v];
    int end   = base[(b << 15) + v];
    float4 acc = make_float4(0.f, 0.f, 0.f, 0.f);
    const short* fT = featT + (((size_t)b << 15) << 6) + lane4 * 4;
    for (int p = start; p < end; ++p) {
        short4 hv = *(const short4*)(fT + ((size_t)p << 6));
        acc.x += bf2f((unsigned short)hv.x);
        acc.y += bf2f((unsigned short)hv.y);
        acc.z += bf2f((unsigned short)hv.z);
        acc.w += bf2f((unsigned short)hv.w);
    }
    float rc = 1.f / fmaxf((float)(end - start), 1.f);
    short4 pk;
    pk.x = f2bf(acc.x * rc); pk.y = f2bf(acc.y * rc);
    pk.z = f2bf(acc.z * rc); pk.w = f2bf(acc.w * rc);
    *(short4*)(vout + (size_t)b * VOXB + ((size_t)(v >> 5) * 34 + (v & 31) + 1) * 64 + lane4 * 4) = pk;
}

// ---------------- 6. weight transpose: [co][ci][27] f32 -> [k][co][ci] bf16 ----
__global__ void k_wprep(const float* __restrict__ w, short* __restrict__ wT) {
    int e = blockIdx.x * 256 + threadIdx.x;   // 27*64*64 = 110592
    int ci = e & 63, co = (e >> 6) & 63, k = e >> 12;
    wT[e] = f2bf(w[(size_t)(co * 64 + ci) * 27 + k]);
}

// ---------------- 7. MFMA implicit-GEMM conv, LDS-staged, fused GN stats -------
// Per block: output tile 4x*4y*32z*64co, 4 waves. Fully-unrolled 27 taps
// (compile-time addresses). Fused epilogue: partial group-norm sums -> st.
__global__ __launch_bounds__(256, 2) void k_conv_mfma(
    const short* __restrict__ vin, const short* __restrict__ wT,
    const float* __restrict__ bias, short* __restrict__ vout, float* __restrict__ st)
{
    __shared__ short lds[36 * 1088];      // 78336 B
    __shared__ float sred[8][2];
    int bid = blockIdx.x;                 // 1024 = 8 xcd * 2 b * 64 tiles
    int xcd = bid & 7, sub = bid >> 3;
    int b = (xcd << 1) | (sub >> 6);
    int tile = sub & 63;
    int x0 = (tile >> 3) << 2, y0 = (tile & 7) << 2;
    int tid = threadIdx.x;
    int wv = tid >> 6, l = tid & 63;
    int lo = l & 31, hi = l >> 5;
    const short* vb = vin + (size_t)b * VOXB;
    int xo = x0 + wv;
    if (tid < 16) ((float*)sred)[tid] = 0.f;

    f32x16 acc[2][4];
    #pragma unroll
    for (int cb = 0; cb < 2; ++cb)
        #pragma unroll
        for (int j = 0; j < 4; ++j)
            #pragma unroll
            for (int i = 0; i < 16; ++i) acc[cb][j][i] = 0.f;

    #pragma unroll
    for (int h = 0; h < 2; ++h) {
        if (h) __syncthreads();
        for (int e = tid; e < 4896; e += 256) {
            int line = e / 136, r = e - line * 136;
            int z = r >> 2, q = r & 3;
            int xx = line / 6, yy = line - xx * 6;
            int xi = x0 + xx - 1, yi = y0 + yy - 1;
            int4 v = make_int4(0, 0, 0, 0);
            if ((unsigned)xi < 32u && (unsigned)yi < 32u)
                v = *(const int4*)(vb + ((size_t)(xi * 32 + yi) * 34 + z) * 64 + h * 32 + q * 8);
            int dst = line * 1088 + z * 32 + ((q * 8) ^ ((z & 3) << 3));
            *(int4*)(lds + dst) = v;
        }
        __syncthreads();
        const short* whb = wT + h * 32 + lo * 64 + hi * 8;
        #pragma unroll
        for (int dx = 0; dx < 3; ++dx) {
            #pragma unroll
            for (int dy = 0; dy < 3; ++dy) {
                const short* lbase = lds + ((wv + dx) * 6 + dy) * 1088;
                #pragma unroll
                for (int dz = 0; dz < 3; ++dz) {
                    const int tap = dx * 9 + dy * 3 + dz;
                    const short* wt = whb + tap * 4096;
                    bfx8 a0 = *(const bfx8*)(wt);
                    bfx8 a1 = *(const bfx8*)(wt + 2048);
                    bfx8 a2 = *(const bfx8*)(wt + 16);
                    bfx8 a3 = *(const bfx8*)(wt + 2048 + 16);
                    int zz = dz + lo;
                    int so = (zz & 3) << 3;
                    int s0 = (hi * 8) ^ so;
                    int s1 = (16 + hi * 8) ^ so;
                    const short* bb0 = lbase + zz * 32;
                    #pragma unroll
                    for (int j = 0; j < 4; ++j) {
                        const short* bp = bb0 + j * 1088;
                        bfx8 b0 = *(const bfx8*)(bp + s0);
                        bfx8 b1 = *(const bfx8*)(bp + s1);
                        acc[0][j] = __builtin_amdgcn_mfma_f32_32x32x16_bf16(a0, b0, acc[0][j], 0, 0, 0);
                        acc[1][j] = __builtin_amdgcn_mfma_f32_32x32x16_bf16(a1, b0, acc[1][j], 0, 0, 0);
                        acc[0][j] = __builtin_amdgcn_mfma_f32_32x32x16_bf16(a2, b1, acc[0][j], 0, 0, 0);
                        acc[1][j] = __builtin_amdgcn_mfma_f32_32x32x16_bf16(a3, b1, acc[1][j], 0, 0, 0);
                    }
                }
            }
        }
    }

    // epilogue: bias + bf16 store + fused GN partial sums
    float gs[8], gs2[8];
    #pragma unroll
    for (int g = 0; g < 8; ++g) { gs[g] = 0.f; gs2[g] = 0.f; }
    short* ob = vout + (size_t)b * VOXB;
    #pragma unroll
    for (int cb = 0; cb < 2; ++cb) {
        #pragma unroll
        for (int j = 0; j < 4; ++j) {
            size_t rb = ((size_t)(xo * 32 + y0 + j) * 34 + 1 + lo) * 64;
            #pragma unroll
            for (int q = 0; q < 4; ++q) {
                int co0 = cb * 32 + hi * 4 + q * 8;
                float v0 = acc[cb][j][q * 4 + 0] + bias[co0 + 0];
                float v1 = acc[cb][j][q * 4 + 1] + bias[co0 + 1];
                float v2 = acc[cb][j][q * 4 + 2] + bias[co0 + 2];
                float v3 = acc[cb][j][q * 4 + 3] + bias[co0 + 3];
                int g = cb * 4 + q;
                gs[g] += v0 + v1 + v2 + v3;
                gs2[g] += v0 * v0 + v1 * v1 + v2 * v2 + v3 * v3;
                short4 pk;
                pk.x = f2bf(v0); pk.y = f2bf(v1); pk.z = f2bf(v2); pk.w = f2bf(v3);
                *(short4*)(ob + rb + co0) = pk;
            }
        }
    }
    #pragma unroll
    for (int g = 0; g < 8; ++g) {
        float s = gs[g], s2 = gs2[g];
        #pragma unroll
        for (int o = 32; o > 0; o >>= 1) { s += __shfl_down(s, o); s2 += __shfl_down(s2, o); }
        if (l == 0) { atomicAdd(&sred[g][0], s); atomicAdd(&sred[g][1], s2); }
    }
    __syncthreads();
    if (tid < 8) {
        atomicAdd(&st[((b << 3) + tid) * 2 + 0], sred[tid][0]);
        atomicAdd(&st[((b << 3) + tid) * 2 + 1], sred[tid][1]);
    }
}

// ---------------- 8. GN apply + swish, in place on padded bf16 volume ----------
__global__ void k_gn_apply_b(short* __restrict__ v, const float* __restrict__ st,
                             const float* __restrict__ gamma, const float* __restrict__ beta) {
    int e = blockIdx.x * 256 + threadIdx.x;   // over 16*32768*8
    int cg = e & 7, vx = (e >> 3) & 32767, b = e >> 18;
    float s = st[(b * 8 + cg) * 2 + 0], s2 = st[(b * 8 + cg) * 2 + 1];
    float mean = s * (1.f / 262144.f);
    float var = s2 * (1.f / 262144.f) - mean * mean;
    float rstd = rsqrtf(var + 1e-5f);
    short* p = v + (size_t)b * VOXB + ((size_t)(vx >> 5) * 34 + (vx & 31) + 1) * 64 + cg * 8;
    usx8 hv = *(const usx8*)p;
    usx8 ov;
    #pragma unroll
    for (int i = 0; i < 8; ++i) {
        int co = cg * 8 + i;
        float f = bf2f(hv[i]);
        float g = (f - mean) * rstd * gamma[co] + beta[co];
        float sw = g / (1.f + __expf(-g));
        ov[i] = (unsigned short)f2bf(sw);
    }
    *(usx8*)p = ov;
}

// ---------------- 9. point GEMM -> bf16 pre-GN scratch + fused GN stats --------
__global__ __launch_bounds__(256) void k_point(const float* __restrict__ feat,
                                               const float* __restrict__ wp,
                                               const float* __restrict__ bp,
                                               short* __restrict__ pbuf,
                                               float* __restrict__ stp) {
    __shared__ float s_f[64][64];
    __shared__ float s_w[64][68];
    __shared__ float sred[8][2];
    int nblk = blockIdx.x * 64;
    int b = blockIdx.y;
    int tid = threadIdx.x;
    if (tid < 16) ((float*)sred)[tid] = 0.f;
    const float* fb = feat + (((size_t)b * CCH) << 15);
    for (int e = tid; e < 64 * 64; e += 256) {
        int c = e >> 6, nn = e & 63;
        s_f[c][nn] = fb[(((size_t)c) << 15) + nblk + nn];
        s_w[nn][c] = wp[e];
    }
    __syncthreads();
    int o0 = (tid >> 4) << 2;
    int n0 = (tid & 15) << 2;
    float acc[4][4] = {{0.f}};
    for (int c = 0; c < 64; ++c) {
        float4 fv = *(const float4*)&s_f[c][n0];
        float4 wv = *(const float4*)&s_w[c][o0];
        float fvv[4] = {fv.x, fv.y, fv.z, fv.w};
        float wvv[4] = {wv.x, wv.y, wv.z, wv.w};
        #pragma unroll
        for (int j = 0; j < 4; ++j)
            #pragma unroll
            for (int i = 0; i < 4; ++i) acc[j][i] += wvv[j] * fvv[i];
    }
    float s = 0.f, s2 = 0.f;
    #pragma unroll
    for (int j = 0; j < 4; ++j) {
        float bb = bp[o0 + j];
        short* op = pbuf + (((size_t)(b * CCH + o0 + j)) << 15) + nblk + n0;
        short4 pk;
        float v0 = acc[j][0] + bb, v1 = acc[j][1] + bb;
        float v2 = acc[j][2] + bb, v3 = acc[j][3] + bb;
        s += v0 + v1 + v2 + v3;
        s2 += v0 * v0 + v1 * v1 + v2 * v2 + v3 * v3;
        pk.x = f2bf(v0); pk.y = f2bf(v1); pk.z = f2bf(v2); pk.w = f2bf(v3);
        *(short4*)op = pk;
    }
    int g = o0 >> 3;
    atomicAdd(&sred[g][0], s);
    atomicAdd(&sred[g][1], s2);
    __syncthreads();
    if (tid < 8) {
        atomicAdd(&stp[(b * 8 + tid) * 2 + 0], sred[tid][0]);
        atomicAdd(&stp[(b * 8 + tid) * 2 + 1], sred[tid][1]);
    }
}

// ---------------- 10. final: devox gather + point GN/swish + add ---------------
__global__ void k_final(const short* __restrict__ h, const float* __restrict__ normc,
                        const float* __restrict__ stp, const float* __restrict__ gp,
                        const float* __restrict__ bep, const short* __restrict__ pbuf,
                        float* __restrict__ out1) {
    int tid = threadIdx.x;
    int s = tid & 7, pp = tid >> 3;
    int pt = blockIdx.x * 32 + pp;
    int b = pt >> 15, n = pt & 32767;
    const float* nb = normc + (size_t)b * 3 * NPT;
    float nx = nb[n], ny = nb[NPT + n], nz = nb[2 * NPT + n];
    float fxf = floorf(nx), fyf = floorf(ny), fzf = floorf(nz);
    float fx = nx - fxf, fy = ny - fyf, fz = nz - fzf;
    int x0 = (int)fxf; x0 = x0 < 31 ? x0 : 31;
    int y0 = (int)fyf; y0 = y0 < 31 ? y0 : 31;
    int z0 = (int)fzf; z0 = z0 < 31 ? z0 : 31;
    int x1 = x0 + 1 < 31 ? x0 + 1 : 31;
    int y1 = y0 + 1 < 31 ? y0 + 1 : 31;
    int z1 = z0 + 1 < 31 ? z0 + 1 : 31;
    float wx0 = 1.f - fx, wx1 = fx, wy0 = 1.f - fy, wy1 = fy, wz0 = 1.f - fz, wz1 = fz;
    const short* hb = h + (size_t)b * VOXB + s * 8;
    float acc[8];
    #pragma unroll
    for (int i = 0; i < 8; ++i) acc[i] = 0.f;
    #pragma unroll
    for (int cx = 0; cx < 2; ++cx) {
        int xi = cx ? x1 : x0; float wxx = cx ? wx1 : wx0;
        #pragma unroll
        for (int cy = 0; cy < 2; ++cy) {
            int yi = cy ? y1 : y0; float wyy = cy ? wy1 : wy0;
            #pragma unroll
            for (int cz = 0; cz < 2; ++cz) {
                int zi = cz ? z1 : z0; float wzz = cz ? wz1 : wz0;
                float w = wxx * wyy * wzz;
                usx8 hv = *(const usx8*)(hb + ((size_t)(xi * 32 + yi) * 34 + zi + 1) * 64);
                #pragma unroll
                for (int i = 0; i < 8; ++i) acc[i] = fmaf(w, bf2f(hv[i]), acc[i]);
            }
        }
    }
    float ss = stp[(b * 8 + s) * 2 + 0], ss2 = stp[(b * 8 + s) * 2 + 1];
    float mean = ss * (1.f / 262144.f);
    float rstd = rsqrtf(ss2 * (1.f / 262144.f) - mean * mean + 1e-5f);
    const short* pb = pbuf + (((size_t)(b * CCH)) << 15) + n;
    #pragma unroll
    for (int i = 0; i < 8; ++i) {
        int co = s * 8 + i;
        float* op = out1 + (((size_t)(b * CCH + co)) << 15) + n;
        float pv = bf2f((unsigned short)pb[((size_t)co) << 15]);
        float g = (pv - mean) * rstd * gp[co] + bep[co];
        float sw = g / (1.f + __expf(-g));
        *op = acc[i] + sw;
    }
}

// --------------------------------- launcher ------------------------------------
extern "C" void kernel_launch(void* const* d_in, const int* in_sizes, int n_in,
                              void* d_out, int out_size, void* d_ws, size_t ws_size,
                              hipStream_t stream) {
    const float* feat   = (const float*)d_in[0];
    const float* coords = (const float*)d_in[1];
    const float* w1  = (const float*)d_in[2];
    const float* b1  = (const float*)d_in[3];
    const float* g1  = (const float*)d_in[4];
    const float* be1 = (const float*)d_in[5];
    const float* w2  = (const float*)d_in[6];
    const float* b2  = (const float*)d_in[7];
    const float* g2  = (const float*)d_in[8];
    const float* be2 = (const float*)d_in[9];
    const float* wp  = (const float*)d_in[10];
    const float* bp  = (const float*)d_in[11];
    const float* gp  = (const float*)d_in[12];
    const float* bep = (const float*)d_in[13];

    float* out1 = (float*)d_out;
    float* out2 = out1 + (size_t)BB * CCH * NPT;

    // workspace layout (~216 MB)
    // region0 [0, 134MB): featT bf16 (67MB) -> voxT_mid bf16 (71MB) -> pbuf bf16 (67MB)
    const size_t reg0Bytes = (size_t)BB * NPT * CCH * 4;
    short* featT    = (short*)d_ws;
    short* voxT_mid = (short*)d_ws;
    short* pbuf     = (short*)d_ws;
    short* voxT_in  = (short*)((char*)d_ws + reg0Bytes);
    char* p = (char*)voxT_in + (size_t)BB * VOXB * 2;
    int*   hist   = (int*)p;  p += (size_t)BB * R3 * 4;
    int*   startB = (int*)p;  p += (size_t)BB * R3 * 4;
    int*   base   = (int*)p;  p += (size_t)BB * R3 * 4;
    float* normc = (float*)p; p += (size_t)BB * 3 * NPT * 4;
    int*   vidx  = (int*)p;   p += (size_t)BB * NPT * 4;
    short* wT1   = (short*)p; p += 110592 * 2;
    short* wT2   = (short*)p; p += 110592 * 2;
    float* st1   = (float*)p; p += 256 * 4;
    float* st2   = (float*)p; p += 256 * 4;
    float* stp   = (float*)p; p += 256 * 4;
    float* csum  = (float*)p; p += 64 * 4;
    int*   cmax  = (int*)p;   p += 16 * 4;

    hipMemsetAsync(voxT_in, 0, (size_t)BB * VOXB * 2, stream);
    hipMemsetAsync(hist, 0, (size_t)BB * R3 * 4, stream);
    hipMemsetAsync(st1, 0, (256 * 3 + 64 + 16) * 4, stream);  // st1,st2,stp,csum,cmax contiguous

    k_cstat_sum<<<128, 256, 0, stream>>>(coords, csum);
    k_cstat_max<<<128, 256, 0, stream>>>(coords, csum, cmax);
    k_norm_idx<<<(BB * NPT) / 256, 256, 0, stream>>>(coords, csum, cmax, normc, vidx, hist, out2);
    k_prefix<<<BB, 1024, 0, stream>>>(hist, startB, base);
    k_reorder<<<(BB * NPT) / 64, 256, 0, stream>>>(feat, vidx, base, featT);
    k_vox_accum<<<(BB * R3 * 16) / 256, 256, 0, stream>>>(featT, startB, base, voxT_in);
    k_wprep<<<432, 256, 0, stream>>>(w1, wT1);
    k_wprep<<<432, 256, 0, stream>>>(w2, wT2);

    // featT dead -> region0 becomes voxT_mid (pads must be zero)
    hipMemsetAsync(voxT_mid, 0, (size_t)BB * VOXB * 2, stream);

    k_conv_mfma<<<1024, 256, 0, stream>>>(voxT_in, wT1, b1, voxT_mid, st1);
    k_gn_apply_b<<<(BB * R3 * 8) / 256, 256, 0, stream>>>(voxT_mid, st1, g1, be1);

    k_conv_mfma<<<1024, 256, 0, stream>>>(voxT_mid, wT2, b2, voxT_in, st2);  // voxT_in pads still zero
    k_gn_apply_b<<<(BB * R3 * 8) / 256, 256, 0, stream>>>(voxT_in, st2, g2, be2);

    // voxT_mid dead -> region0 becomes pbuf
    k_point<<<dim3(NPT / 64, BB), 256, 0, stream>>>(feat, wp, bp, pbuf, stp);

    k_final<<<(BB * NPT) / 32, 256, 0, stream>>>(voxT_in, normc, stp, gp, bep, pbuf, out1);
}

// Round 7
// 745.115 us; speedup vs baseline: 8.6179x; 1.0164x over previous
//
#include <hip/hip_runtime.h>
#include <hip/hip_bf16.h>
#include <math.h>

#define BB   16
#define CCH  64
#define NPT  32768
#define RR   32
#define R3   32768
#define GSZ  262144
#define VOXB 2228224   // 32*32*34*64 bf16 elements per batch (z padded to 34)

typedef __attribute__((ext_vector_type(8))) short bfx8;
typedef __attribute__((ext_vector_type(8))) unsigned short usx8;
typedef __attribute__((ext_vector_type(16))) float f32x16;

__device__ __forceinline__ short f2bf(float f) {
    unsigned u = __builtin_bit_cast(unsigned, f);
    u += 0x7fff + ((u >> 16) & 1);
    return (short)(u >> 16);
}
__device__ __forceinline__ float bf2f(unsigned short s) {
    unsigned u = ((unsigned)s) << 16;
    return __builtin_bit_cast(float, u);
}

// ---------------- block reduction helpers -------------------------------------
__device__ __forceinline__ float blockReduceSumF(float v) {
    __shared__ float sm[16];
    #pragma unroll
    for (int o = 32; o > 0; o >>= 1) v += __shfl_down(v, o);
    __syncthreads();
    if ((threadIdx.x & 63) == 0) sm[threadIdx.x >> 6] = v;
    __syncthreads();
    float s = 0.f;
    int nw = blockDim.x >> 6;
    for (int i = 0; i < nw; ++i) s += sm[i];
    return s;
}

__device__ __forceinline__ float blockReduceMaxF(float v) {
    __shared__ float sm[16];
    #pragma unroll
    for (int o = 32; o > 0; o >>= 1) v = fmaxf(v, __shfl_down(v, o));
    __syncthreads();
    if ((threadIdx.x & 63) == 0) sm[threadIdx.x >> 6] = v;
    __syncthreads();
    float s = sm[0];
    int nw = blockDim.x >> 6;
    for (int i = 1; i < nw; ++i) s = fmaxf(s, sm[i]);
    return s;
}

// ---------------- 1a. coord partial sums (128 blocks) --------------------------
__global__ void k_cstat_sum(const float* __restrict__ coords, float* __restrict__ csum) {
    int b = blockIdx.x >> 3, seg = blockIdx.x & 7;
    const float* cb = coords + (size_t)b * 3 * NPT;
    int n0 = seg << 12;
    float sx = 0.f, sy = 0.f, sz = 0.f;
    for (int n = n0 + threadIdx.x; n < n0 + 4096; n += 256) {
        sx += cb[n]; sy += cb[NPT + n]; sz += cb[2 * NPT + n];
    }
    sx = blockReduceSumF(sx);
    sy = blockReduceSumF(sy);
    sz = blockReduceSumF(sz);
    if (threadIdx.x == 0) {
        atomicAdd(&csum[b * 4 + 0], sx);
        atomicAdd(&csum[b * 4 + 1], sy);
        atomicAdd(&csum[b * 4 + 2], sz);
    }
}

// ---------------- 1b. coord max distance (128 blocks, int-bits atomicMax) ------
__global__ void k_cstat_max(const float* __restrict__ coords, const float* __restrict__ csum,
                            int* __restrict__ cmax) {
    int b = blockIdx.x >> 3, seg = blockIdx.x & 7;
    const float* cb = coords + (size_t)b * 3 * NPT;
    float mx = csum[b * 4 + 0] * (1.f / NPT);
    float my = csum[b * 4 + 1] * (1.f / NPT);
    float mz = csum[b * 4 + 2] * (1.f / NPT);
    int n0 = seg << 12;
    float mn = 0.f;
    for (int n = n0 + threadIdx.x; n < n0 + 4096; n += 256) {
        float x = cb[n] - mx, y = cb[NPT + n] - my, z = cb[2 * NPT + n] - mz;
        mn = fmaxf(mn, sqrtf(x * x + y * y + z * z));
    }
    mn = blockReduceMaxF(mn);
    if (threadIdx.x == 0) atomicMax(&cmax[b], __float_as_int(mn));
}

// ---------------- 2. normalized coords + voxel idx + histogram + passthrough ---
__global__ void k_norm_idx(const float* __restrict__ coords, const float* __restrict__ csum,
                           const int* __restrict__ cmax,
                           float* __restrict__ normc, int* __restrict__ vidx,
                           int* __restrict__ hist, float* __restrict__ out2) {
    int t = blockIdx.x * 256 + threadIdx.x;
    int b = t >> 15, n = t & 32767;
    float mx = csum[b * 4 + 0] * (1.f / NPT);
    float my = csum[b * 4 + 1] * (1.f / NPT);
    float mz = csum[b * 4 + 2] * (1.f / NPT);
    float scale = 2.f * __int_as_float(cmax[b]);
    const float* cb = coords + (size_t)b * 3 * NPT;
    float x = cb[n], y = cb[NPT + n], z = cb[2 * NPT + n];
    float nx = fminf(fmaxf(((x - mx) / scale + 0.5f) * 32.f, 0.f), 31.f);
    float ny = fminf(fmaxf(((y - my) / scale + 0.5f) * 32.f, 0.f), 31.f);
    float nz = fminf(fmaxf(((z - mz) / scale + 0.5f) * 32.f, 0.f), 31.f);
    float* nb = normc + (size_t)b * 3 * NPT;
    nb[n] = nx; nb[NPT + n] = ny; nb[2 * NPT + n] = nz;
    int vx = (int)rintf(nx), vy = (int)rintf(ny), vz = (int)rintf(nz);
    int v = (vx * 32 + vy) * 32 + vz;
    vidx[t] = v;
    atomicAdd(&hist[(b << 15) + v], 1);
    float* o2 = out2 + (size_t)b * 3 * NPT;
    o2[n] = x; o2[NPT + n] = y; o2[2 * NPT + n] = z;
}

// ---------------- 3. per-batch exclusive prefix over 32768 bins ----------------
__global__ __launch_bounds__(1024) void k_prefix(const int* __restrict__ hist,
                                                 int* __restrict__ startB,
                                                 int* __restrict__ base) {
    int b = blockIdx.x;
    int tid = threadIdx.x;
    const int* h = hist + (b << 15);
    int loc[32];
    int s = 0;
    #pragma unroll
    for (int j = 0; j < 32; ++j) { loc[j] = h[tid * 32 + j]; s += loc[j]; }
    __shared__ int sm[1024];
    sm[tid] = s;
    __syncthreads();
    for (int o = 1; o < 1024; o <<= 1) {
        int v = (tid >= o) ? sm[tid - o] : 0;
        __syncthreads();
        sm[tid] += v;
        __syncthreads();
    }
    int run = (tid ? sm[tid - 1] : 0);
    #pragma unroll
    for (int j = 0; j < 32; ++j) {
        int idx = (b << 15) + tid * 32 + j;
        startB[idx] = run;
        base[idx] = run;
        run += loc[j];
    }
}

// ---------------- 4. reorder: feat [b][c][n] f32 -> featT [b][slot][c] bf16 ----
__global__ __launch_bounds__(256) void k_reorder(const float* __restrict__ feat,
                                                 const int* __restrict__ vidx,
                                                 int* __restrict__ base,
                                                 short* __restrict__ featT) {
    __shared__ float tile[64][65];
    __shared__ int sslot[64];
    int blk = blockIdx.x;             // 8192 = 16 b * 512
    int b = blk >> 9;
    int n0 = (blk & 511) << 6;
    int tid = threadIdx.x;
    const float* fb = feat + ((size_t)b << 21);
    for (int e = tid; e < 64 * 64; e += 256) {
        int c = e >> 6, nn = e & 63;
        tile[c][nn] = fb[((size_t)c << 15) + n0 + nn];
    }
    if (tid < 64) {
        int v = vidx[(b << 15) + n0 + tid];
        sslot[tid] = atomicAdd(&base[(b << 15) + v], 1);
    }
    __syncthreads();
    int p = tid >> 2, q = tid & 3;    // 4 threads/point, 16 ch each
    int slot = sslot[p];
    short* dst = featT + (((size_t)((b << 15) + slot)) << 6) + q * 16;
    unsigned pk[8];
    #pragma unroll
    for (int k = 0; k < 8; ++k) {
        unsigned lo16 = (unsigned short)f2bf(tile[q * 16 + 2 * k][p]);
        unsigned hi16 = (unsigned short)f2bf(tile[q * 16 + 2 * k + 1][p]);
        pk[k] = lo16 | (hi16 << 16);
    }
    *(int4*)dst = make_int4(pk[0], pk[1], pk[2], pk[3]);
    *(int4*)(dst + 8) = make_int4(pk[4], pk[5], pk[6], pk[7]);
}

// ---------------- 5. voxel accumulate + divide + bf16 padded layout ------------
__global__ void k_vox_accum(const short* __restrict__ featT, const int* __restrict__ startB,
                            const int* __restrict__ base, short* __restrict__ vout) {
    int t = blockIdx.x * 256 + threadIdx.x;   // over B*R3*16
    int lane4 = t & 15;
    int v = (t >> 4) & 32767;
    int b = t >> 19;
    int start = startB[(b << 15) + v];
    int end   = base[(b << 15) + v];
    float4 acc = make_float4(0.f, 0.f, 0.f, 0.f);
    const short* fT = featT + (((size_t)b << 15) << 6) + lane4 * 4;
    for (int p = start; p < end; ++p) {
        short4 hv = *(const short4*)(fT + ((size_t)p << 6));
        acc.x += bf2f((unsigned short)hv.x);
        acc.y += bf2f((unsigned short)hv.y);
        acc.z += bf2f((unsigned short)hv.z);
        acc.w += bf2f((unsigned short)hv.w);
    }
    float rc = 1.f / fmaxf((float)(end - start), 1.f);
    short4 pk;
    pk.x = f2bf(acc.x * rc); pk.y = f2bf(acc.y * rc);
    pk.z = f2bf(acc.z * rc); pk.w = f2bf(acc.w * rc);
    *(short4*)(vout + (size_t)b * VOXB + ((size_t)(v >> 5) * 34 + (v & 31) + 1) * 64 + lane4 * 4) = pk;
}

// ---------------- 6. zero only the z-pad slices of a padded volume -------------
__global__ void k_padzero(short* __restrict__ v) {
    int t = blockIdx.x * 256 + threadIdx.x;   // 262144 = 16b * 1024xy * 2zp * 8q
    int q = t & 7, zp = (t >> 3) & 1, xy = (t >> 4) & 1023, b = t >> 14;
    int z = zp ? 33 : 0;
    *(int4*)(v + (size_t)b * VOXB + ((size_t)xy * 34 + z) * 64 + q * 8) = make_int4(0, 0, 0, 0);
}

// ---------------- 7. weight transpose: [co][ci][27] f32 -> [k][co][ci] bf16 ----
__global__ void k_wprep(const float* __restrict__ w, short* __restrict__ wT) {
    int e = blockIdx.x * 256 + threadIdx.x;   // 27*64*64 = 110592
    int ci = e & 63, co = (e >> 6) & 63, k = e >> 12;
    wT[e] = f2bf(w[(size_t)(co * 64 + ci) * 27 + k]);
}

// ---------------- 8. MFMA implicit-GEMM conv, LDS-staged, line-stationary ------
// Per block: output tile 4x*4y*32z*64co, 4 waves. For each (dx,dz,ci-slot):
// loop the 6 staged y-lines; each B-fragment read feeds up to 3 dy-taps x 2
// co-blocks (avg 4 MFMA per ds_read_b128, 2x fewer LDS reads than tap-order).
// Fused epilogue: bias + bf16 store + partial group-norm sums.
__global__ __launch_bounds__(256, 2) void k_conv_mfma(
    const short* __restrict__ vin, const short* __restrict__ wT,
    const float* __restrict__ bias, short* __restrict__ vout, float* __restrict__ st)
{
    __shared__ short lds[36 * 1088];      // 78336 B
    __shared__ float sred[8][2];
    int bid = blockIdx.x;                 // 1024 = 8 xcd * 2 b * 64 tiles
    int xcd = bid & 7, sub = bid >> 3;
    int b = (xcd << 1) | (sub >> 6);
    int tile = sub & 63;
    int x0 = (tile >> 3) << 2, y0 = (tile & 7) << 2;
    int tid = threadIdx.x;
    int wv = tid >> 6, l = tid & 63;
    int lo = l & 31, hi = l >> 5;
    const short* vb = vin + (size_t)b * VOXB;
    int xo = x0 + wv;
    if (tid < 16) ((float*)sred)[tid] = 0.f;

    f32x16 acc[2][4];
    #pragma unroll
    for (int cb = 0; cb < 2; ++cb)
        #pragma unroll
        for (int j = 0; j < 4; ++j)
            #pragma unroll
            for (int i = 0; i < 16; ++i) acc[cb][j][i] = 0.f;

    #pragma unroll
    for (int h = 0; h < 2; ++h) {
        if (h) __syncthreads();
        for (int e = tid; e < 4896; e += 256) {
            int line = e / 136, r = e - line * 136;
            int z = r >> 2, q = r & 3;
            int xx = line / 6, yy = line - xx * 6;
            int xi = x0 + xx - 1, yi = y0 + yy - 1;
            int4 v = make_int4(0, 0, 0, 0);
            if ((unsigned)xi < 32u && (unsigned)yi < 32u)
                v = *(const int4*)(vb + ((size_t)(xi * 32 + yi) * 34 + z) * 64 + h * 32 + q * 8);
            int dst = line * 1088 + z * 32 + ((q * 8) ^ ((z & 3) << 3));
            *(int4*)(lds + dst) = v;
        }
        __syncthreads();
        const short* wbase = wT + lo * 64 + h * 32 + hi * 8;
        #pragma unroll
        for (int dx = 0; dx < 3; ++dx) {
            const short* ldsx = lds + ((wv + dx) * 6) * 1088;
            #pragma unroll
            for (int dz = 0; dz < 3; ++dz) {
                int zz = lo + dz;
                int swz = (zz & 3) << 3;
                const short* bcol = ldsx + zz * 32;
                #pragma unroll
                for (int s = 0; s < 2; ++s) {
                    int slot = (s * 16 + hi * 8) ^ swz;
                    const short* wt0 = wbase + (dx * 9 + dz) * 4096 + s * 16;
                    bfx8 wA0 = *(const bfx8*)(wt0);
                    bfx8 wB0 = *(const bfx8*)(wt0 + 2048);
                    bfx8 wA1 = *(const bfx8*)(wt0 + 3 * 4096);
                    bfx8 wB1 = *(const bfx8*)(wt0 + 3 * 4096 + 2048);
                    bfx8 wA2 = *(const bfx8*)(wt0 + 6 * 4096);
                    bfx8 wB2 = *(const bfx8*)(wt0 + 6 * 4096 + 2048);
                    #pragma unroll
                    for (int L = 0; L < 6; ++L) {
                        bfx8 bv = *(const bfx8*)(bcol + L * 1088 + slot);
                        if (L <= 3) {   // dy=0 -> j=L
                            acc[0][L] = __builtin_amdgcn_mfma_f32_32x32x16_bf16(wA0, bv, acc[0][L], 0, 0, 0);
                            acc[1][L] = __builtin_amdgcn_mfma_f32_32x32x16_bf16(wB0, bv, acc[1][L], 0, 0, 0);
                        }
                        if (L >= 1 && L <= 4) {   // dy=1 -> j=L-1
                            acc[0][L-1] = __builtin_amdgcn_mfma_f32_32x32x16_bf16(wA1, bv, acc[0][L-1], 0, 0, 0);
                            acc[1][L-1] = __builtin_amdgcn_mfma_f32_32x32x16_bf16(wB1, bv, acc[1][L-1], 0, 0, 0);
                        }
                        if (L >= 2) {   // dy=2 -> j=L-2
                            acc[0][L-2] = __builtin_amdgcn_mfma_f32_32x32x16_bf16(wA2, bv, acc[0][L-2], 0, 0, 0);
                            acc[1][L-2] = __builtin_amdgcn_mfma_f32_32x32x16_bf16(wB2, bv, acc[1][L-2], 0, 0, 0);
                        }
                    }
                }
            }
        }
    }

    // epilogue: bias + bf16 store + fused GN partial sums
    float gs[8], gs2[8];
    #pragma unroll
    for (int g = 0; g < 8; ++g) { gs[g] = 0.f; gs2[g] = 0.f; }
    short* ob = vout + (size_t)b * VOXB;
    #pragma unroll
    for (int cb = 0; cb < 2; ++cb) {
        #pragma unroll
        for (int j = 0; j < 4; ++j) {
            size_t rb = ((size_t)(xo * 32 + y0 + j) * 34 + 1 + lo) * 64;
            #pragma unroll
            for (int q = 0; q < 4; ++q) {
                int co0 = cb * 32 + hi * 4 + q * 8;
                float v0 = acc[cb][j][q * 4 + 0] + bias[co0 + 0];
                float v1 = acc[cb][j][q * 4 + 1] + bias[co0 + 1];
                float v2 = acc[cb][j][q * 4 + 2] + bias[co0 + 2];
                float v3 = acc[cb][j][q * 4 + 3] + bias[co0 + 3];
                int g = cb * 4 + q;
                gs[g] += v0 + v1 + v2 + v3;
                gs2[g] += v0 * v0 + v1 * v1 + v2 * v2 + v3 * v3;
                short4 pk;
                pk.x = f2bf(v0); pk.y = f2bf(v1); pk.z = f2bf(v2); pk.w = f2bf(v3);
                *(short4*)(ob + rb + co0) = pk;
            }
        }
    }
    #pragma unroll
    for (int g = 0; g < 8; ++g) {
        float s = gs[g], s2 = gs2[g];
        #pragma unroll
        for (int o = 32; o > 0; o >>= 1) { s += __shfl_down(s, o); s2 += __shfl_down(s2, o); }
        if (l == 0) { atomicAdd(&sred[g][0], s); atomicAdd(&sred[g][1], s2); }
    }
    __syncthreads();
    if (tid < 8) {
        atomicAdd(&st[((b << 3) + tid) * 2 + 0], sred[tid][0]);
        atomicAdd(&st[((b << 3) + tid) * 2 + 1], sred[tid][1]);
    }
}

// ---------------- 9. GN apply + swish, in place on padded bf16 volume ----------
__global__ void k_gn_apply_b(short* __restrict__ v, const float* __restrict__ st,
                             const float* __restrict__ gamma, const float* __restrict__ beta) {
    int e = blockIdx.x * 256 + threadIdx.x;   // over 16*32768*8
    int cg = e & 7, vx = (e >> 3) & 32767, b = e >> 18;
    float s = st[(b * 8 + cg) * 2 + 0], s2 = st[(b * 8 + cg) * 2 + 1];
    float mean = s * (1.f / 262144.f);
    float var = s2 * (1.f / 262144.f) - mean * mean;
    float rstd = rsqrtf(var + 1e-5f);
    short* p = v + (size_t)b * VOXB + ((size_t)(vx >> 5) * 34 + (vx & 31) + 1) * 64 + cg * 8;
    usx8 hv = *(const usx8*)p;
    usx8 ov;
    #pragma unroll
    for (int i = 0; i < 8; ++i) {
        int co = cg * 8 + i;
        float f = bf2f(hv[i]);
        float g = (f - mean) * rstd * gamma[co] + beta[co];
        float sw = g / (1.f + __expf(-g));
        ov[i] = (unsigned short)f2bf(sw);
    }
    *(usx8*)p = ov;
}

// ---------------- 10. point GEMM -> bf16 pre-GN scratch + fused GN stats -------
__global__ __launch_bounds__(256) void k_point(const float* __restrict__ feat,
                                               const float* __restrict__ wp,
                                               const float* __restrict__ bp,
                                               short* __restrict__ pbuf,
                                               float* __restrict__ stp) {
    __shared__ float s_f[64][64];
    __shared__ float s_w[64][68];
    __shared__ float sred[8][2];
    int nblk = blockIdx.x * 64;
    int b = blockIdx.y;
    int tid = threadIdx.x;
    if (tid < 16) ((float*)sred)[tid] = 0.f;
    const float* fb = feat + (((size_t)b * CCH) << 15);
    for (int e = tid; e < 64 * 64; e += 256) {
        int c = e >> 6, nn = e & 63;
        s_f[c][nn] = fb[(((size_t)c) << 15) + nblk + nn];
        s_w[nn][c] = wp[e];
    }
    __syncthreads();
    int o0 = (tid >> 4) << 2;
    int n0 = (tid & 15) << 2;
    float acc[4][4] = {{0.f}};
    for (int c = 0; c < 64; ++c) {
        float4 fv = *(const float4*)&s_f[c][n0];
        float4 wv = *(const float4*)&s_w[c][o0];
        float fvv[4] = {fv.x, fv.y, fv.z, fv.w};
        float wvv[4] = {wv.x, wv.y, wv.z, wv.w};
        #pragma unroll
        for (int j = 0; j < 4; ++j)
            #pragma unroll
            for (int i = 0; i < 4; ++i) acc[j][i] += wvv[j] * fvv[i];
    }
    float s = 0.f, s2 = 0.f;
    #pragma unroll
    for (int j = 0; j < 4; ++j) {
        float bb = bp[o0 + j];
        short* op = pbuf + (((size_t)(b * CCH + o0 + j)) << 15) + nblk + n0;
        short4 pk;
        float v0 = acc[j][0] + bb, v1 = acc[j][1] + bb;
        float v2 = acc[j][2] + bb, v3 = acc[j][3] + bb;
        s += v0 + v1 + v2 + v3;
        s2 += v0 * v0 + v1 * v1 + v2 * v2 + v3 * v3;
        pk.x = f2bf(v0); pk.y = f2bf(v1); pk.z = f2bf(v2); pk.w = f2bf(v3);
        *(short4*)op = pk;
    }
    int g = o0 >> 3;
    atomicAdd(&sred[g][0], s);
    atomicAdd(&sred[g][1], s2);
    __syncthreads();
    if (tid < 8) {
        atomicAdd(&stp[(b * 8 + tid) * 2 + 0], sred[tid][0]);
        atomicAdd(&stp[(b * 8 + tid) * 2 + 1], sred[tid][1]);
    }
}

// ---------------- 11. final: devox gather + point GN/swish + add ---------------
__global__ void k_final(const short* __restrict__ h, const float* __restrict__ normc,
                        const float* __restrict__ stp, const float* __restrict__ gp,
                        const float* __restrict__ bep, const short* __restrict__ pbuf,
                        float* __restrict__ out1) {
    int tid = threadIdx.x;
    int s = tid & 7, pp = tid >> 3;
    int pt = blockIdx.x * 32 + pp;
    int b = pt >> 15, n = pt & 32767;
    const float* nb = normc + (size_t)b * 3 * NPT;
    float nx = nb[n], ny = nb[NPT + n], nz = nb[2 * NPT + n];
    float fxf = floorf(nx), fyf = floorf(ny), fzf = floorf(nz);
    float fx = nx - fxf, fy = ny - fyf, fz = nz - fzf;
    int x0 = (int)fxf; x0 = x0 < 31 ? x0 : 31;
    int y0 = (int)fyf; y0 = y0 < 31 ? y0 : 31;
    int z0 = (int)fzf; z0 = z0 < 31 ? z0 : 31;
    int x1 = x0 + 1 < 31 ? x0 + 1 : 31;
    int y1 = y0 + 1 < 31 ? y0 + 1 : 31;
    int z1 = z0 + 1 < 31 ? z0 + 1 : 31;
    float wx0 = 1.f - fx, wx1 = fx, wy0 = 1.f - fy, wy1 = fy, wz0 = 1.f - fz, wz1 = fz;
    const short* hb = h + (size_t)b * VOXB + s * 8;
    float acc[8];
    #pragma unroll
    for (int i = 0; i < 8; ++i) acc[i] = 0.f;
    #pragma unroll
    for (int cx = 0; cx < 2; ++cx) {
        int xi = cx ? x1 : x0; float wxx = cx ? wx1 : wx0;
        #pragma unroll
        for (int cy = 0; cy < 2; ++cy) {
            int yi = cy ? y1 : y0; float wyy = cy ? wy1 : wy0;
            #pragma unroll
            for (int cz = 0; cz < 2; ++cz) {
                int zi = cz ? z1 : z0; float wzz = cz ? wz1 : wz0;
                float w = wxx * wyy * wzz;
                usx8 hv = *(const usx8*)(hb + ((size_t)(xi * 32 + yi) * 34 + zi + 1) * 64);
                #pragma unroll
                for (int i = 0; i < 8; ++i) acc[i] = fmaf(w, bf2f(hv[i]), acc[i]);
            }
        }
    }
    float ss = stp[(b * 8 + s) * 2 + 0], ss2 = stp[(b * 8 + s) * 2 + 1];
    float mean = ss * (1.f / 262144.f);
    float rstd = rsqrtf(ss2 * (1.f / 262144.f) - mean * mean + 1e-5f);
    const short* pb = pbuf + (((size_t)(b * CCH)) << 15) + n;
    #pragma unroll
    for (int i = 0; i < 8; ++i) {
        int co = s * 8 + i;
        float* op = out1 + (((size_t)(b * CCH + co)) << 15) + n;
        float pv = bf2f((unsigned short)pb[((size_t)co) << 15]);
        float g = (pv - mean) * rstd * gp[co] + bep[co];
        float sw = g / (1.f + __expf(-g));
        *op = acc[i] + sw;
    }
}

// --------------------------------- launcher ------------------------------------
extern "C" void kernel_launch(void* const* d_in, const int* in_sizes, int n_in,
                              void* d_out, int out_size, void* d_ws, size_t ws_size,
                              hipStream_t stream) {
    const float* feat   = (const float*)d_in[0];
    const float* coords = (const float*)d_in[1];
    const float* w1  = (const float*)d_in[2];
    const float* b1  = (const float*)d_in[3];
    const float* g1  = (const float*)d_in[4];
    const float* be1 = (const float*)d_in[5];
    const float* w2  = (const float*)d_in[6];
    const float* b2  = (const float*)d_in[7];
    const float* g2  = (const float*)d_in[8];
    const float* be2 = (const float*)d_in[9];
    const float* wp  = (const float*)d_in[10];
    const float* bp  = (const float*)d_in[11];
    const float* gp  = (const float*)d_in[12];
    const float* bep = (const float*)d_in[13];

    float* out1 = (float*)d_out;
    float* out2 = out1 + (size_t)BB * CCH * NPT;

    // workspace layout (~216 MB)
    // region0 [0, 134MB): featT bf16 (67MB) -> voxT_mid bf16 (71MB) -> pbuf bf16 (67MB)
    const size_t reg0Bytes = (size_t)BB * NPT * CCH * 4;
    short* featT    = (short*)d_ws;
    short* voxT_mid = (short*)d_ws;
    short* pbuf     = (short*)d_ws;
    short* voxT_in  = (short*)((char*)d_ws + reg0Bytes);
    char* p = (char*)voxT_in + (size_t)BB * VOXB * 2;
    int*   hist   = (int*)p;  p += (size_t)BB * R3 * 4;
    int*   startB = (int*)p;  p += (size_t)BB * R3 * 4;
    int*   base   = (int*)p;  p += (size_t)BB * R3 * 4;
    float* normc = (float*)p; p += (size_t)BB * 3 * NPT * 4;
    int*   vidx  = (int*)p;   p += (size_t)BB * NPT * 4;
    short* wT1   = (short*)p; p += 110592 * 2;
    short* wT2   = (short*)p; p += 110592 * 2;
    float* st1   = (float*)p; p += 256 * 4;
    float* st2   = (float*)p; p += 256 * 4;
    float* stp   = (float*)p; p += 256 * 4;
    float* csum  = (float*)p; p += 64 * 4;
    int*   cmax  = (int*)p;   p += 16 * 4;

    hipMemsetAsync(hist, 0, (size_t)BB * R3 * 4, stream);
    hipMemsetAsync(st1, 0, (256 * 3 + 64 + 16) * 4, stream);  // st1,st2,stp,csum,cmax contiguous

    k_padzero<<<1024, 256, 0, stream>>>(voxT_in);
    k_cstat_sum<<<128, 256, 0, stream>>>(coords, csum);
    k_cstat_max<<<128, 256, 0, stream>>>(coords, csum, cmax);
    k_norm_idx<<<(BB * NPT) / 256, 256, 0, stream>>>(coords, csum, cmax, normc, vidx, hist, out2);
    k_prefix<<<BB, 1024, 0, stream>>>(hist, startB, base);
    k_reorder<<<(BB * NPT) / 64, 256, 0, stream>>>(feat, vidx, base, featT);
    k_vox_accum<<<(BB * R3 * 16) / 256, 256, 0, stream>>>(featT, startB, base, voxT_in);
    k_wprep<<<432, 256, 0, stream>>>(w1, wT1);
    k_wprep<<<432, 256, 0, stream>>>(w2, wT2);

    // featT dead -> region0 becomes voxT_mid; zero only its z-pads
    k_padzero<<<1024, 256, 0, stream>>>(voxT_mid);

    k_conv_mfma<<<1024, 256, 0, stream>>>(voxT_in, wT1, b1, voxT_mid, st1);
    k_gn_apply_b<<<(BB * R3 * 8) / 256, 256, 0, stream>>>(voxT_mid, st1, g1, be1);

    k_conv_mfma<<<1024, 256, 0, stream>>>(voxT_mid, wT2, b2, voxT_in, st2);  // voxT_in pads still zero
    k_gn_apply_b<<<(BB * R3 * 8) / 256, 256, 0, stream>>>(voxT_in, st2, g2, be2);

    // voxT_mid dead -> region0 becomes pbuf
    k_point<<<dim3(NPT / 64, BB), 256, 0, stream>>>(feat, wp, bp, pbuf, stp);

    k_final<<<(BB * NPT) / 32, 256, 0, stream>>>(voxT_in, normc, stp, gp, bep, pbuf, out1);
}

// Round 8
// 720.204 us; speedup vs baseline: 8.9159x; 1.0346x over previous
//
#include <hip/hip_runtime.h>
#include <hip/hip_bf16.h>
#include <math.h>

#define BB   16
#define CCH  64
#define NPT  32768
#define RR   32
#define R3   32768
#define GSZ  262144
#define VOXB 2228224   // 32*32*34*64 bf16 elements per batch (z padded to 34)

typedef __attribute__((ext_vector_type(8))) short bfx8;
typedef __attribute__((ext_vector_type(8))) unsigned short usx8;
typedef __attribute__((ext_vector_type(16))) float f32x16;

__device__ __forceinline__ short f2bf(float f) {
    unsigned u = __builtin_bit_cast(unsigned, f);
    u += 0x7fff + ((u >> 16) & 1);
    return (short)(u >> 16);
}
__device__ __forceinline__ float bf2f(unsigned short s) {
    unsigned u = ((unsigned)s) << 16;
    return __builtin_bit_cast(float, u);
}

// ---------------- block reduction helpers -------------------------------------
__device__ __forceinline__ float blockReduceSumF(float v) {
    __shared__ float sm[16];
    #pragma unroll
    for (int o = 32; o > 0; o >>= 1) v += __shfl_down(v, o);
    __syncthreads();
    if ((threadIdx.x & 63) == 0) sm[threadIdx.x >> 6] = v;
    __syncthreads();
    float s = 0.f;
    int nw = blockDim.x >> 6;
    for (int i = 0; i < nw; ++i) s += sm[i];
    return s;
}

__device__ __forceinline__ float blockReduceMaxF(float v) {
    __shared__ float sm[16];
    #pragma unroll
    for (int o = 32; o > 0; o >>= 1) v = fmaxf(v, __shfl_down(v, o));
    __syncthreads();
    if ((threadIdx.x & 63) == 0) sm[threadIdx.x >> 6] = v;
    __syncthreads();
    float s = sm[0];
    int nw = blockDim.x >> 6;
    for (int i = 1; i < nw; ++i) s = fmaxf(s, sm[i]);
    return s;
}

// ---------------- 1a. coord partial sums (128 blocks) --------------------------
__global__ void k_cstat_sum(const float* __restrict__ coords, float* __restrict__ csum) {
    int b = blockIdx.x >> 3, seg = blockIdx.x & 7;
    const float* cb = coords + (size_t)b * 3 * NPT;
    int n0 = seg << 12;
    float sx = 0.f, sy = 0.f, sz = 0.f;
    for (int n = n0 + threadIdx.x; n < n0 + 4096; n += 256) {
        sx += cb[n]; sy += cb[NPT + n]; sz += cb[2 * NPT + n];
    }
    sx = blockReduceSumF(sx);
    sy = blockReduceSumF(sy);
    sz = blockReduceSumF(sz);
    if (threadIdx.x == 0) {
        atomicAdd(&csum[b * 4 + 0], sx);
        atomicAdd(&csum[b * 4 + 1], sy);
        atomicAdd(&csum[b * 4 + 2], sz);
    }
}

// ---------------- 1b. coord max distance (128 blocks, int-bits atomicMax) ------
__global__ void k_cstat_max(const float* __restrict__ coords, const float* __restrict__ csum,
                            int* __restrict__ cmax) {
    int b = blockIdx.x >> 3, seg = blockIdx.x & 7;
    const float* cb = coords + (size_t)b * 3 * NPT;
    float mx = csum[b * 4 + 0] * (1.f / NPT);
    float my = csum[b * 4 + 1] * (1.f / NPT);
    float mz = csum[b * 4 + 2] * (1.f / NPT);
    int n0 = seg << 12;
    float mn = 0.f;
    for (int n = n0 + threadIdx.x; n < n0 + 4096; n += 256) {
        float x = cb[n] - mx, y = cb[NPT + n] - my, z = cb[2 * NPT + n] - mz;
        mn = fmaxf(mn, sqrtf(x * x + y * y + z * z));
    }
    mn = blockReduceMaxF(mn);
    if (threadIdx.x == 0) atomicMax(&cmax[b], __float_as_int(mn));
}

// ---------------- 2. normalized coords + voxel idx + histogram + passthrough ---
__global__ void k_norm_idx(const float* __restrict__ coords, const float* __restrict__ csum,
                           const int* __restrict__ cmax,
                           float* __restrict__ normc, int* __restrict__ vidx,
                           int* __restrict__ hist, float* __restrict__ out2) {
    int t = blockIdx.x * 256 + threadIdx.x;
    int b = t >> 15, n = t & 32767;
    float mx = csum[b * 4 + 0] * (1.f / NPT);
    float my = csum[b * 4 + 1] * (1.f / NPT);
    float mz = csum[b * 4 + 2] * (1.f / NPT);
    float scale = 2.f * __int_as_float(cmax[b]);
    const float* cb = coords + (size_t)b * 3 * NPT;
    float x = cb[n], y = cb[NPT + n], z = cb[2 * NPT + n];
    float nx = fminf(fmaxf(((x - mx) / scale + 0.5f) * 32.f, 0.f), 31.f);
    float ny = fminf(fmaxf(((y - my) / scale + 0.5f) * 32.f, 0.f), 31.f);
    float nz = fminf(fmaxf(((z - mz) / scale + 0.5f) * 32.f, 0.f), 31.f);
    float* nb = normc + (size_t)b * 3 * NPT;
    nb[n] = nx; nb[NPT + n] = ny; nb[2 * NPT + n] = nz;
    int vx = (int)rintf(nx), vy = (int)rintf(ny), vz = (int)rintf(nz);
    int v = (vx * 32 + vy) * 32 + vz;
    vidx[t] = v;
    atomicAdd(&hist[(b << 15) + v], 1);
    float* o2 = out2 + (size_t)b * 3 * NPT;
    o2[n] = x; o2[NPT + n] = y; o2[2 * NPT + n] = z;
}

// ---------------- 3. per-batch exclusive prefix over 32768 bins ----------------
__global__ __launch_bounds__(1024) void k_prefix(const int* __restrict__ hist,
                                                 int* __restrict__ startB,
                                                 int* __restrict__ base) {
    int b = blockIdx.x;
    int tid = threadIdx.x;
    const int* h = hist + (b << 15);
    int loc[32];
    int s = 0;
    #pragma unroll
    for (int j = 0; j < 32; ++j) { loc[j] = h[tid * 32 + j]; s += loc[j]; }
    __shared__ int sm[1024];
    sm[tid] = s;
    __syncthreads();
    for (int o = 1; o < 1024; o <<= 1) {
        int v = (tid >= o) ? sm[tid - o] : 0;
        __syncthreads();
        sm[tid] += v;
        __syncthreads();
    }
    int run = (tid ? sm[tid - 1] : 0);
    #pragma unroll
    for (int j = 0; j < 32; ++j) {
        int idx = (b << 15) + tid * 32 + j;
        startB[idx] = run;
        base[idx] = run;
        run += loc[j];
    }
}

// ---------------- 4. reorder: feat [b][c][n] f32 -> featT [b][slot][c] bf16 ----
__global__ __launch_bounds__(256) void k_reorder(const float* __restrict__ feat,
                                                 const int* __restrict__ vidx,
                                                 int* __restrict__ base,
                                                 short* __restrict__ featT) {
    __shared__ float tile[64][65];
    __shared__ int sslot[64];
    int blk = blockIdx.x;             // 8192 = 16 b * 512
    int b = blk >> 9;
    int n0 = (blk & 511) << 6;
    int tid = threadIdx.x;
    const float* fb = feat + ((size_t)b << 21);
    for (int e = tid; e < 64 * 16; e += 256) {
        int c = e >> 4, n4 = e & 15;
        float4 v4 = *(const float4*)(fb + ((size_t)c << 15) + n0 + n4 * 4);
        tile[c][n4 * 4 + 0] = v4.x; tile[c][n4 * 4 + 1] = v4.y;
        tile[c][n4 * 4 + 2] = v4.z; tile[c][n4 * 4 + 3] = v4.w;
    }
    if (tid < 64) {
        int v = vidx[(b << 15) + n0 + tid];
        sslot[tid] = atomicAdd(&base[(b << 15) + v], 1);
    }
    __syncthreads();
    int p = tid >> 2, q = tid & 3;    // 4 threads/point, 16 ch each
    int slot = sslot[p];
    short* dst = featT + (((size_t)((b << 15) + slot)) << 6) + q * 16;
    unsigned pk[8];
    #pragma unroll
    for (int k = 0; k < 8; ++k) {
        unsigned lo16 = (unsigned short)f2bf(tile[q * 16 + 2 * k][p]);
        unsigned hi16 = (unsigned short)f2bf(tile[q * 16 + 2 * k + 1][p]);
        pk[k] = lo16 | (hi16 << 16);
    }
    *(int4*)dst = make_int4(pk[0], pk[1], pk[2], pk[3]);
    *(int4*)(dst + 8) = make_int4(pk[4], pk[5], pk[6], pk[7]);
}

// ---------------- 5. voxel accumulate + divide + bf16 padded layout ------------
__global__ void k_vox_accum(const short* __restrict__ featT, const int* __restrict__ startB,
                            const int* __restrict__ base, short* __restrict__ vout) {
    int t = blockIdx.x * 256 + threadIdx.x;   // over B*R3*16
    int lane4 = t & 15;
    int v = (t >> 4) & 32767;
    int b = t >> 19;
    int start = startB[(b << 15) + v];
    int end   = base[(b << 15) + v];
    float4 acc = make_float4(0.f, 0.f, 0.f, 0.f);
    const short* fT = featT + (((size_t)b << 15) << 6) + lane4 * 4;
    for (int p = start; p < end; ++p) {
        short4 hv = *(const short4*)(fT + ((size_t)p << 6));
        acc.x += bf2f((unsigned short)hv.x);
        acc.y += bf2f((unsigned short)hv.y);
        acc.z += bf2f((unsigned short)hv.z);
        acc.w += bf2f((unsigned short)hv.w);
    }
    float rc = 1.f / fmaxf((float)(end - start), 1.f);
    short4 pk;
    pk.x = f2bf(acc.x * rc); pk.y = f2bf(acc.y * rc);
    pk.z = f2bf(acc.z * rc); pk.w = f2bf(acc.w * rc);
    *(short4*)(vout + (size_t)b * VOXB + ((size_t)(v >> 5) * 34 + (v & 31) + 1) * 64 + lane4 * 4) = pk;
}

// ---------------- 6. zero only the z-pad slices of a padded volume -------------
__global__ void k_padzero(short* __restrict__ v) {
    int t = blockIdx.x * 256 + threadIdx.x;   // 262144 = 16b * 1024xy * 2zp * 8q
    int q = t & 7, zp = (t >> 3) & 1, xy = (t >> 4) & 1023, b = t >> 14;
    int z = zp ? 33 : 0;
    *(int4*)(v + (size_t)b * VOXB + ((size_t)xy * 34 + z) * 64 + q * 8) = make_int4(0, 0, 0, 0);
}

// ---------------- 7. weight transpose: [co][ci][27] f32 -> [k][co][ci] bf16 ----
__global__ void k_wprep(const float* __restrict__ w, short* __restrict__ wT) {
    int e = blockIdx.x * 256 + threadIdx.x;   // 27*64*64 = 110592
    int ci = e & 63, co = (e >> 6) & 63, k = e >> 12;
    wT[e] = f2bf(w[(size_t)(co * 64 + ci) * 27 + k]);
}

// ---------------- 8. MFMA implicit-GEMM conv, 8-wave, optional fused GN-in -----
// 512 threads = 8 waves = (2 co-halves x 4 x-lines). Per wave: acc[4] f32x16
// (64 AGPR) -> 16 waves/CU resident. FUSE: apply GN+swish (params stin/gin/bein)
// to input during LDS staging (conv2 path). Fused epilogue GN stats -> st.
template<bool FUSE>
__global__ __launch_bounds__(512, 4) void k_conv_mfma(
    const short* __restrict__ vin, const short* __restrict__ wT,
    const float* __restrict__ bias,
    const float* __restrict__ stin, const float* __restrict__ gin,
    const float* __restrict__ bein,
    short* __restrict__ vout, float* __restrict__ st)
{
    __shared__ short lds[36 * 1088];      // 78336 B
    __shared__ float sred[8][2];
    int bid = blockIdx.x;                 // 1024 = 8 xcd * 2 b * 64 tiles
    int xcd = bid & 7, sub = bid >> 3;
    int b = (xcd << 1) | (sub >> 6);
    int tile = sub & 63;
    int x0 = (tile >> 3) << 2, y0 = (tile & 7) << 2;
    int tid = threadIdx.x;
    int wv8 = tid >> 6;
    int cb = wv8 & 1, xl = wv8 >> 1;      // co-half, x-line
    int l = tid & 63, lo = l & 31, hi = l >> 5;
    const short* vb = vin + (size_t)b * VOXB;
    int xo = x0 + xl;
    if (tid < 16) ((float*)sred)[tid] = 0.f;

    f32x16 acc[4];
    #pragma unroll
    for (int j = 0; j < 4; ++j)
        #pragma unroll
        for (int i = 0; i < 16; ++i) acc[j][i] = 0.f;

    #pragma unroll
    for (int h = 0; h < 2; ++h) {
        if (h) __syncthreads();
        for (int e = tid; e < 4896; e += 512) {
            int line = e / 136, r = e - line * 136;
            int z = r >> 2, q = r & 3;
            int xx = line / 6, yy = line - xx * 6;
            int xi = x0 + xx - 1, yi = y0 + yy - 1;
            bool inb = ((unsigned)xi < 32u) && ((unsigned)yi < 32u);
            int4 v = make_int4(0, 0, 0, 0);
            if (inb)
                v = *(const int4*)(vb + ((size_t)(xi * 32 + yi) * 34 + z) * 64 + h * 32 + q * 8);
            if (FUSE) {
                if (inb && z >= 1 && z <= 32) {
                    int ci0 = h * 32 + q * 8, cg = ci0 >> 3;
                    float s = stin[((b << 3) + cg) * 2 + 0];
                    float s2 = stin[((b << 3) + cg) * 2 + 1];
                    float mean = s * (1.f / 262144.f);
                    float rstd = rsqrtf(s2 * (1.f / 262144.f) - mean * mean + 1e-5f);
                    float4 ga = *(const float4*)(gin + ci0);
                    float4 gb = *(const float4*)(gin + ci0 + 4);
                    float4 ba = *(const float4*)(bein + ci0);
                    float4 bb = *(const float4*)(bein + ci0 + 4);
                    float gm[8] = {ga.x, ga.y, ga.z, ga.w, gb.x, gb.y, gb.z, gb.w};
                    float bt[8] = {ba.x, ba.y, ba.z, ba.w, bb.x, bb.y, bb.z, bb.w};
                    unsigned short* hv = (unsigned short*)&v;
                    #pragma unroll
                    for (int i = 0; i < 8; ++i) {
                        float f = bf2f(hv[i]);
                        float g = (f - mean) * rstd * gm[i] + bt[i];
                        float sw = g / (1.f + __expf(-g));
                        hv[i] = (unsigned short)f2bf(sw);
                    }
                }
            }
            int dst = line * 1088 + z * 32 + ((q * 8) ^ ((z & 3) << 3));
            *(int4*)(lds + dst) = v;
        }
        __syncthreads();
        const short* wbase = wT + lo * 64 + h * 32 + hi * 8 + cb * 2048;
        #pragma unroll
        for (int dx = 0; dx < 3; ++dx) {
            const short* ldsx = lds + ((xl + dx) * 6) * 1088;
            #pragma unroll
            for (int dz = 0; dz < 3; ++dz) {
                int zz = lo + dz;
                int swz = (zz & 3) << 3;
                const short* bcol = ldsx + zz * 32;
                #pragma unroll
                for (int s = 0; s < 2; ++s) {
                    int slot = (s * 16 + hi * 8) ^ swz;
                    const short* wt0 = wbase + (dx * 9 + dz) * 4096 + s * 16;
                    bfx8 w0 = *(const bfx8*)(wt0);
                    bfx8 w1 = *(const bfx8*)(wt0 + 3 * 4096);
                    bfx8 w2 = *(const bfx8*)(wt0 + 6 * 4096);
                    #pragma unroll
                    for (int L = 0; L < 6; ++L) {
                        bfx8 bv = *(const bfx8*)(bcol + L * 1088 + slot);
                        if (L <= 3)
                            acc[L] = __builtin_amdgcn_mfma_f32_32x32x16_bf16(w0, bv, acc[L], 0, 0, 0);
                        if (L >= 1 && L <= 4)
                            acc[L-1] = __builtin_amdgcn_mfma_f32_32x32x16_bf16(w1, bv, acc[L-1], 0, 0, 0);
                        if (L >= 2)
                            acc[L-2] = __builtin_amdgcn_mfma_f32_32x32x16_bf16(w2, bv, acc[L-2], 0, 0, 0);
                    }
                }
            }
        }
    }

    // epilogue: bias + bf16 store + fused GN partial sums (this wave's co-half)
    float gs[4], gs2[4];
    #pragma unroll
    for (int g = 0; g < 4; ++g) { gs[g] = 0.f; gs2[g] = 0.f; }
    short* ob = vout + (size_t)b * VOXB;
    #pragma unroll
    for (int j = 0; j < 4; ++j) {
        size_t rb = ((size_t)(xo * 32 + y0 + j) * 34 + 1 + lo) * 64;
        #pragma unroll
        for (int q = 0; q < 4; ++q) {
            int co0 = cb * 32 + hi * 4 + q * 8;
            float v0 = acc[j][q * 4 + 0] + bias[co0 + 0];
            float v1 = acc[j][q * 4 + 1] + bias[co0 + 1];
            float v2 = acc[j][q * 4 + 2] + bias[co0 + 2];
            float v3 = acc[j][q * 4 + 3] + bias[co0 + 3];
            gs[q] += v0 + v1 + v2 + v3;
            gs2[q] += v0 * v0 + v1 * v1 + v2 * v2 + v3 * v3;
            short4 pk;
            pk.x = f2bf(v0); pk.y = f2bf(v1); pk.z = f2bf(v2); pk.w = f2bf(v3);
            *(short4*)(ob + rb + co0) = pk;
        }
    }
    #pragma unroll
    for (int q = 0; q < 4; ++q) {
        float s = gs[q], s2 = gs2[q];
        #pragma unroll
        for (int o = 32; o > 0; o >>= 1) { s += __shfl_down(s, o); s2 += __shfl_down(s2, o); }
        if (l == 0) { atomicAdd(&sred[cb * 4 + q][0], s); atomicAdd(&sred[cb * 4 + q][1], s2); }
    }
    __syncthreads();
    if (tid < 8) {
        atomicAdd(&st[((b << 3) + tid) * 2 + 0], sred[tid][0]);
        atomicAdd(&st[((b << 3) + tid) * 2 + 1], sred[tid][1]);
    }
}

// ---------------- 9. GN apply + swish, in place on padded bf16 volume ----------
__global__ void k_gn_apply_b(short* __restrict__ v, const float* __restrict__ st,
                             const float* __restrict__ gamma, const float* __restrict__ beta) {
    int e = blockIdx.x * 256 + threadIdx.x;   // over 16*32768*8
    int cg = e & 7, vx = (e >> 3) & 32767, b = e >> 18;
    float s = st[(b * 8 + cg) * 2 + 0], s2 = st[(b * 8 + cg) * 2 + 1];
    float mean = s * (1.f / 262144.f);
    float var = s2 * (1.f / 262144.f) - mean * mean;
    float rstd = rsqrtf(var + 1e-5f);
    short* p = v + (size_t)b * VOXB + ((size_t)(vx >> 5) * 34 + (vx & 31) + 1) * 64 + cg * 8;
    usx8 hv = *(const usx8*)p;
    usx8 ov;
    #pragma unroll
    for (int i = 0; i < 8; ++i) {
        int co = cg * 8 + i;
        float f = bf2f(hv[i]);
        float g = (f - mean) * rstd * gamma[co] + beta[co];
        float sw = g / (1.f + __expf(-g));
        ov[i] = (unsigned short)f2bf(sw);
    }
    *(usx8*)p = ov;
}

// ---------------- 10. point GEMM -> bf16 pre-GN scratch + fused GN stats -------
__global__ __launch_bounds__(256) void k_point(const float* __restrict__ feat,
                                               const float* __restrict__ wp,
                                               const float* __restrict__ bp,
                                               short* __restrict__ pbuf,
                                               float* __restrict__ stp) {
    __shared__ float s_f[64][64];
    __shared__ float s_w[64][68];
    __shared__ float sred[8][2];
    int nblk = blockIdx.x * 64;
    int b = blockIdx.y;
    int tid = threadIdx.x;
    if (tid < 16) ((float*)sred)[tid] = 0.f;
    const float* fb = feat + (((size_t)b * CCH) << 15);
    for (int e = tid; e < 64 * 64; e += 256) {
        int c = e >> 6, nn = e & 63;
        s_f[c][nn] = fb[(((size_t)c) << 15) + nblk + nn];
        s_w[nn][c] = wp[e];
    }
    __syncthreads();
    int o0 = (tid >> 4) << 2;
    int n0 = (tid & 15) << 2;
    float acc[4][4] = {{0.f}};
    for (int c = 0; c < 64; ++c) {
        float4 fv = *(const float4*)&s_f[c][n0];
        float4 wv = *(const float4*)&s_w[c][o0];
        float fvv[4] = {fv.x, fv.y, fv.z, fv.w};
        float wvv[4] = {wv.x, wv.y, wv.z, wv.w};
        #pragma unroll
        for (int j = 0; j < 4; ++j)
            #pragma unroll
            for (int i = 0; i < 4; ++i) acc[j][i] += wvv[j] * fvv[i];
    }
    float s = 0.f, s2 = 0.f;
    #pragma unroll
    for (int j = 0; j < 4; ++j) {
        float bb = bp[o0 + j];
        short* op = pbuf + (((size_t)(b * CCH + o0 + j)) << 15) + nblk + n0;
        short4 pk;
        float v0 = acc[j][0] + bb, v1 = acc[j][1] + bb;
        float v2 = acc[j][2] + bb, v3 = acc[j][3] + bb;
        s += v0 + v1 + v2 + v3;
        s2 += v0 * v0 + v1 * v1 + v2 * v2 + v3 * v3;
        pk.x = f2bf(v0); pk.y = f2bf(v1); pk.z = f2bf(v2); pk.w = f2bf(v3);
        *(short4*)op = pk;
    }
    int g = o0 >> 3;
    atomicAdd(&sred[g][0], s);
    atomicAdd(&sred[g][1], s2);
    __syncthreads();
    if (tid < 8) {
        atomicAdd(&stp[(b * 8 + tid) * 2 + 0], sred[tid][0]);
        atomicAdd(&stp[(b * 8 + tid) * 2 + 1], sred[tid][1]);
    }
}

// ---------------- 11. final: devox gather + point GN/swish + add ---------------
__global__ void k_final(const short* __restrict__ h, const float* __restrict__ normc,
                        const float* __restrict__ stp, const float* __restrict__ gp,
                        const float* __restrict__ bep, const short* __restrict__ pbuf,
                        float* __restrict__ out1) {
    int tid = threadIdx.x;
    int s = tid & 7, pp = tid >> 3;
    int pt = blockIdx.x * 32 + pp;
    int b = pt >> 15, n = pt & 32767;
    const float* nb = normc + (size_t)b * 3 * NPT;
    float nx = nb[n], ny = nb[NPT + n], nz = nb[2 * NPT + n];
    float fxf = floorf(nx), fyf = floorf(ny), fzf = floorf(nz);
    float fx = nx - fxf, fy = ny - fyf, fz = nz - fzf;
    int x0 = (int)fxf; x0 = x0 < 31 ? x0 : 31;
    int y0 = (int)fyf; y0 = y0 < 31 ? y0 : 31;
    int z0 = (int)fzf; z0 = z0 < 31 ? z0 : 31;
    int x1 = x0 + 1 < 31 ? x0 + 1 : 31;
    int y1 = y0 + 1 < 31 ? y0 + 1 : 31;
    int z1 = z0 + 1 < 31 ? z0 + 1 : 31;
    float wx0 = 1.f - fx, wx1 = fx, wy0 = 1.f - fy, wy1 = fy, wz0 = 1.f - fz, wz1 = fz;
    const short* hb = h + (size_t)b * VOXB + s * 8;
    float acc[8];
    #pragma unroll
    for (int i = 0; i < 8; ++i) acc[i] = 0.f;
    #pragma unroll
    for (int cx = 0; cx < 2; ++cx) {
        int xi = cx ? x1 : x0; float wxx = cx ? wx1 : wx0;
        #pragma unroll
        for (int cy = 0; cy < 2; ++cy) {
            int yi = cy ? y1 : y0; float wyy = cy ? wy1 : wy0;
            #pragma unroll
            for (int cz = 0; cz < 2; ++cz) {
                int zi = cz ? z1 : z0; float wzz = cz ? wz1 : wz0;
                float w = wxx * wyy * wzz;
                usx8 hv = *(const usx8*)(hb + ((size_t)(xi * 32 + yi) * 34 + zi + 1) * 64);
                #pragma unroll
                for (int i = 0; i < 8; ++i) acc[i] = fmaf(w, bf2f(hv[i]), acc[i]);
            }
        }
    }
    float ss = stp[(b * 8 + s) * 2 + 0], ss2 = stp[(b * 8 + s) * 2 + 1];
    float mean = ss * (1.f / 262144.f);
    float rstd = rsqrtf(ss2 * (1.f / 262144.f) - mean * mean + 1e-5f);
    const short* pb = pbuf + (((size_t)(b * CCH)) << 15) + n;
    #pragma unroll
    for (int i = 0; i < 8; ++i) {
        int co = s * 8 + i;
        float* op = out1 + (((size_t)(b * CCH + co)) << 15) + n;
        float pv = bf2f((unsigned short)pb[((size_t)co) << 15]);
        float g = (pv - mean) * rstd * gp[co] + bep[co];
        float sw = g / (1.f + __expf(-g));
        *op = acc[i] + sw;
    }
}

// --------------------------------- launcher ------------------------------------
extern "C" void kernel_launch(void* const* d_in, const int* in_sizes, int n_in,
                              void* d_out, int out_size, void* d_ws, size_t ws_size,
                              hipStream_t stream) {
    const float* feat   = (const float*)d_in[0];
    const float* coords = (const float*)d_in[1];
    const float* w1  = (const float*)d_in[2];
    const float* b1  = (const float*)d_in[3];
    const float* g1  = (const float*)d_in[4];
    const float* be1 = (const float*)d_in[5];
    const float* w2  = (const float*)d_in[6];
    const float* b2  = (const float*)d_in[7];
    const float* g2  = (const float*)d_in[8];
    const float* be2 = (const float*)d_in[9];
    const float* wp  = (const float*)d_in[10];
    const float* bp  = (const float*)d_in[11];
    const float* gp  = (const float*)d_in[12];
    const float* bep = (const float*)d_in[13];

    float* out1 = (float*)d_out;
    float* out2 = out1 + (size_t)BB * CCH * NPT;

    // workspace layout (~216 MB)
    // region0 [0, 134MB): featT bf16 (67MB) -> voxT_mid bf16 (71MB) -> pbuf bf16 (67MB)
    const size_t reg0Bytes = (size_t)BB * NPT * CCH * 4;
    short* featT    = (short*)d_ws;
    short* voxT_mid = (short*)d_ws;
    short* pbuf     = (short*)d_ws;
    short* voxT_in  = (short*)((char*)d_ws + reg0Bytes);
    char* p = (char*)voxT_in + (size_t)BB * VOXB * 2;
    int*   hist   = (int*)p;  p += (size_t)BB * R3 * 4;
    int*   startB = (int*)p;  p += (size_t)BB * R3 * 4;
    int*   base   = (int*)p;  p += (size_t)BB * R3 * 4;
    float* normc = (float*)p; p += (size_t)BB * 3 * NPT * 4;
    int*   vidx  = (int*)p;   p += (size_t)BB * NPT * 4;
    short* wT1   = (short*)p; p += 110592 * 2;
    short* wT2   = (short*)p; p += 110592 * 2;
    float* st1   = (float*)p; p += 256 * 4;
    float* st2   = (float*)p; p += 256 * 4;
    float* stp   = (float*)p; p += 256 * 4;
    float* csum  = (float*)p; p += 64 * 4;
    int*   cmax  = (int*)p;   p += 16 * 4;

    hipMemsetAsync(hist, 0, (size_t)BB * R3 * 4, stream);
    hipMemsetAsync(st1, 0, (256 * 3 + 64 + 16) * 4, stream);  // st1,st2,stp,csum,cmax contiguous

    k_padzero<<<1024, 256, 0, stream>>>(voxT_in);
    k_cstat_sum<<<128, 256, 0, stream>>>(coords, csum);
    k_cstat_max<<<128, 256, 0, stream>>>(coords, csum, cmax);
    k_norm_idx<<<(BB * NPT) / 256, 256, 0, stream>>>(coords, csum, cmax, normc, vidx, hist, out2);
    k_prefix<<<BB, 1024, 0, stream>>>(hist, startB, base);
    k_reorder<<<(BB * NPT) / 64, 256, 0, stream>>>(feat, vidx, base, featT);
    k_vox_accum<<<(BB * R3 * 16) / 256, 256, 0, stream>>>(featT, startB, base, voxT_in);
    k_wprep<<<432, 256, 0, stream>>>(w1, wT1);
    k_wprep<<<432, 256, 0, stream>>>(w2, wT2);

    // featT dead -> region0 becomes voxT_mid; zero only its z-pads
    k_padzero<<<1024, 256, 0, stream>>>(voxT_mid);

    // conv1 (no input fuse) -> voxT_mid holds PRE-GN conv1 output + st1 sums
    k_conv_mfma<false><<<1024, 512, 0, stream>>>(voxT_in, wT1, b1,
                                                 nullptr, nullptr, nullptr, voxT_mid, st1);
    // conv2: staging applies GN1+swish on the fly -> voxT_in (pads still zero), st2 sums
    k_conv_mfma<true><<<1024, 512, 0, stream>>>(voxT_mid, wT2, b2,
                                                st1, g1, be1, voxT_in, st2);
    k_gn_apply_b<<<(BB * R3 * 8) / 256, 256, 0, stream>>>(voxT_in, st2, g2, be2);

    // voxT_mid dead -> region0 becomes pbuf
    k_point<<<dim3(NPT / 64, BB), 256, 0, stream>>>(feat, wp, bp, pbuf, stp);

    k_final<<<(BB * NPT) / 32, 256, 0, stream>>>(voxT_in, normc, stp, gp, bep, pbuf, out1);
}